// Round 1
// baseline (3283.889 us; speedup 1.0000x reference)
//
#include <hip/hip_runtime.h>
#include <hip/hip_bf16.h>

typedef unsigned short u16;
typedef float f32x4 __attribute__((ext_vector_type(4)));
typedef __bf16 bf16x8 __attribute__((ext_vector_type(8)));
typedef short s16x8 __attribute__((ext_vector_type(8)));

// ---------------- helpers ----------------

__device__ __forceinline__ u16 f2b(float f) {
  union { __hip_bfloat16 h; u16 u; } c;
  c.h = __float2bfloat16(f);
  return c.u;
}

__device__ __forceinline__ void gload16(const void* g, void* l) {
  __builtin_amdgcn_global_load_lds(
      (const __attribute__((address_space(1))) unsigned int*)g,
      (__attribute__((address_space(3))) unsigned int*)l, 16, 0, 0);
}

__device__ __forceinline__ float block_sum(float v, float* sred) {
  const int tid = threadIdx.x;
#pragma unroll
  for (int off = 32; off >= 1; off >>= 1) v += __shfl_down(v, off);
  if ((tid & 63) == 0) sred[tid >> 6] = v;
  __syncthreads();
  float r = sred[0] + sred[1] + sred[2] + sred[3];
  __syncthreads();
  return r;
}

// ---------------- GEMM core ----------------
// C[128 x RB] (+)= A[128,K] @ Bt[RB,K]^T  with bf16 mfma_f32_16x16x32.
// LDS tile: row-major [ROWS][32] bf16 (64 B/row), 16B slots XOR-swizzled:
// slot' = k8 ^ ((row>>1)&3). global_load_lds needs a LINEAR LDS dest, so the
// swizzle is applied to the per-lane GLOBAL source address instead (m201
// pattern), and the identical XOR is applied on the ds_read side.

template<int ROWS>
__device__ __forceinline__ void stage_tile(const u16* g, int ld, char* ldsb, int tid) {
#pragma unroll
  for (int i = 0; i < ROWS / 64; ++i) {
    int c = i * 256 + tid;
    int row = c >> 2;
    int k8 = (c & 3) ^ ((row >> 1) & 3);
    // LDS base must be wave-uniform: (tid&192)*16 == wave*1024
    gload16(g + (size_t)row * ld + k8 * 8, ldsb + i * 4096 + (tid & 192) * 16);
  }
}

template<int MI, int NI, int WCN>
__device__ __forceinline__ void compute_tile(const char* lA, const char* lB, f32x4 (&acc)[MI][NI]) {
  const int tid = threadIdx.x;
  const int lane = tid & 63;
  const int w = tid >> 6;
  const int wr = w / WCN, wc = w % WCN;
  const int fr = lane & 15, k8 = lane >> 4;
  bf16x8 a[MI], b[NI];
#pragma unroll
  for (int mi = 0; mi < MI; ++mi) {
    int row = wr * (MI * 16) + mi * 16 + fr;
    a[mi] = *(const bf16x8*)(lA + row * 64 + ((k8 ^ ((row >> 1) & 3)) << 4));
  }
#pragma unroll
  for (int ni = 0; ni < NI; ++ni) {
    int row = wc * (NI * 16) + ni * 16 + fr;
    b[ni] = *(const bf16x8*)(lB + row * 64 + ((k8 ^ ((row >> 1) & 3)) << 4));
  }
#pragma unroll
  for (int mi = 0; mi < MI; ++mi)
#pragma unroll
    for (int ni = 0; ni < NI; ++ni)
      acc[mi][ni] = __builtin_amdgcn_mfma_f32_16x16x32_bf16(a[mi], b[ni], acc[mi][ni], 0, 0, 0);
}

template<int MI, int NI, int WRN, int WCN, int RB>
__device__ __forceinline__ void gemm_core(const u16* A, int lda, const u16* B, int ldb,
                                          int nkt, char* lds, f32x4 (&acc)[MI][NI]) {
  const int tid = threadIdx.x;
  const int bufSz = 8192 + RB * 64;
  stage_tile<128>(A, lda, lds, tid);
  stage_tile<RB>(B, ldb, lds + 8192, tid);
  __syncthreads();  // drains vmcnt -> buf0 ready
  int cur = 0;
  for (int kt = 0; kt < nkt; ++kt) {
    if (kt + 1 < nkt) {  // issue next-tile loads BEFORE compute (overlap)
      char* nb = lds + (cur ^ 1) * bufSz;
      stage_tile<128>(A + (size_t)(kt + 1) * 32, lda, nb, tid);
      stage_tile<RB>(B + (size_t)(kt + 1) * 32, ldb, nb + 8192, tid);
    }
    char* cb = lds + cur * bufSz;
    compute_tile<MI, NI, WCN>(cb, cb + 8192, acc);
    __syncthreads();  // vmcnt(0)+lgkmcnt(0)+barrier: next buf ready, cur reusable
    cur ^= 1;
  }
}

// ---------------- kernels ----------------

// x[row] = tok_emb[ctx[row]] + pos_emb[row % 1024]
__global__ __launch_bounds__(256) void embed_kernel(const int* __restrict__ ctx,
    const float* __restrict__ tok, const float* __restrict__ pos, float* __restrict__ x) {
  const int row = blockIdx.x, tid = threadIdx.x;
  const int t = row & 1023;
  const int id = ctx[row];
  float4 a = ((const float4*)(tok + (size_t)id * 1024))[tid];
  float4 p = ((const float4*)(pos + (size_t)t * 1024))[tid];
  a.x += p.x; a.y += p.y; a.z += p.z; a.w += p.w;
  ((float4*)(x + (size_t)row * 1024))[tid] = a;
}

// LN row (D=1024) -> bf16
__global__ __launch_bounds__(256) void layernorm_bf16(const float* __restrict__ x,
    const float* __restrict__ sc, const float* __restrict__ bi, u16* __restrict__ h) {
  __shared__ float sred[4];
  const int row = blockIdx.x, tid = threadIdx.x;
  const float4 v = ((const float4*)(x + (size_t)row * 1024))[tid];
  float mean = block_sum(v.x + v.y + v.z + v.w, sred) * (1.f / 1024.f);
  const float dx = v.x - mean, dy = v.y - mean, dz = v.z - mean, dw = v.w - mean;
  float var = block_sum(dx * dx + dy * dy + dz * dz + dw * dw, sred) * (1.f / 1024.f);
  const float rs = rsqrtf(var + 1e-5f);
  const float4 s4 = ((const float4*)sc)[tid];
  const float4 b4 = ((const float4*)bi)[tid];
  ushort4 o;
  o.x = f2b(dx * rs * s4.x + b4.x);
  o.y = f2b(dy * rs * s4.y + b4.y);
  o.z = f2b(dz * rs * s4.z + b4.z);
  o.w = f2b(dw * rs * s4.w + b4.w);
  ((ushort4*)(h + (size_t)row * 1024))[tid] = o;
}

// fp32 [K=1024, N] -> bf16 [N, 1024] (weight transpose+convert), batched over z
__device__ __forceinline__ void transpose_body(const float* __restrict__ src,
                                               u16* __restrict__ dst, int N) {
  __shared__ float tile[32][33];
  const int tid = threadIdx.x;
  const int tx = tid & 31, ty = tid >> 5;
  const int kt = blockIdx.y * 32, nt = blockIdx.x * 32;
#pragma unroll
  for (int i = 0; i < 4; ++i) {
    int r = ty + i * 8;
    tile[r][tx] = src[(size_t)(kt + r) * N + nt + tx];
  }
  __syncthreads();
#pragma unroll
  for (int i = 0; i < 4; ++i) {
    int r = ty + i * 8;
    dst[(size_t)(nt + r) * 1024 + kt + tx] = f2b(tile[tx][r]);
  }
}

__global__ __launch_bounds__(256) void transpose_cvt(const float* __restrict__ src,
    u16* __restrict__ dst, int N, size_t srcStride, size_t dstStride) {
  transpose_body(src + blockIdx.z * srcStride, dst + blockIdx.z * dstStride, N);
}

__global__ __launch_bounds__(256) void transpose_qkv(const float* __restrict__ wq,
    const float* __restrict__ wk, const float* __restrict__ wv, u16* __restrict__ dst) {
  const int z = blockIdx.z, l = z / 3, which = z - l * 3;
  const float* src = (which == 0 ? wq : (which == 1 ? wk : wv)) + (size_t)l * 1048576;
  u16* d = dst + (size_t)l * 3145728 + (size_t)which * 1048576;
  transpose_body(src, d, 1024);
}

// generic C = A@Bt^T epilogue variants
template<bool BIAS, bool RELU, bool RESID, bool OUTBF>
__global__ __launch_bounds__(256) void gemm_bt(const u16* __restrict__ A, int lda,
    const u16* __restrict__ Bt, int ldb, const float* __restrict__ bias,
    const float* __restrict__ resid, void* __restrict__ out, int ldc, int nkt) {
  __shared__ __align__(128) char lds[2 * 16384];
  const size_t bm = (size_t)blockIdx.y * 128, bn = (size_t)blockIdx.x * 128;
  const f32x4 vz = {0.f, 0.f, 0.f, 0.f};
  f32x4 acc[4][4];
#pragma unroll
  for (int i = 0; i < 4; ++i)
#pragma unroll
    for (int j = 0; j < 4; ++j) acc[i][j] = vz;
  gemm_core<4, 4, 2, 2, 128>(A + bm * lda, lda, Bt + bn * ldb, ldb, nkt, lds, acc);
  const int tid = threadIdx.x, lane = tid & 63, w = tid >> 6;
  const int wr = w >> 1, wc = w & 1, fr = lane & 15, k8 = lane >> 4;
#pragma unroll
  for (int mi = 0; mi < 4; ++mi)
#pragma unroll
    for (int ni = 0; ni < 4; ++ni) {
      const size_t c = bn + wc * 64 + ni * 16 + fr;
      const float bv = BIAS ? bias[c] : 0.f;
#pragma unroll
      for (int j = 0; j < 4; ++j) {
        const size_t r = bm + wr * 64 + mi * 16 + k8 * 4 + j;
        float v = acc[mi][ni][j] + bv;
        if (RELU) v = fmaxf(v, 0.f);
        if (RESID) v += resid[r * (size_t)ldc + c];
        if (OUTBF) ((u16*)out)[r * (size_t)ldc + c] = f2b(v);
        else       ((float*)out)[r * (size_t)ldc + c] = v;
      }
    }
}

// scores[t,s] = (q.k)/8, causal-masked, fp32. qkv layout [2048, 3072] bf16.
__global__ __launch_bounds__(256) void attn_scores(const u16* __restrict__ qkv,
    float* __restrict__ scores, int bh0) {
  const int st = blockIdx.x, tt = blockIdx.y;
  if (st > tt) return;  // fully-masked tile
  const int bh = bh0 + blockIdx.z;
  const int b = bh >> 4, h = bh & 15;
  __shared__ __align__(128) char lds[2 * 16384];
  const u16* A = qkv + (size_t)(b * 1024 + tt * 128) * 3072 + h * 64;          // q
  const u16* B = qkv + (size_t)(b * 1024 + st * 128) * 3072 + 1024 + h * 64;   // k
  const f32x4 vz = {0.f, 0.f, 0.f, 0.f};
  f32x4 acc[4][4];
#pragma unroll
  for (int i = 0; i < 4; ++i)
#pragma unroll
    for (int j = 0; j < 4; ++j) acc[i][j] = vz;
  gemm_core<4, 4, 2, 2, 128>(A, 3072, B, 3072, 2, lds, acc);
  const int tid = threadIdx.x, lane = tid & 63, w = tid >> 6;
  const int wr = w >> 1, wc = w & 1, fr = lane & 15, k8 = lane >> 4;
  float* srow = scores + (size_t)blockIdx.z * (1024 * 1024);
#pragma unroll
  for (int mi = 0; mi < 4; ++mi)
#pragma unroll
    for (int ni = 0; ni < 4; ++ni) {
      const int s = st * 128 + wc * 64 + ni * 16 + fr;
#pragma unroll
      for (int j = 0; j < 4; ++j) {
        const int t = tt * 128 + wr * 64 + mi * 16 + k8 * 4 + j;
        float v = acc[mi][ni][j] * 0.125f;
        if (s > t) v = -1e30f;
        srow[(size_t)t * 1024 + s] = v;
      }
    }
}

// row softmax over s<=t; writes bf16 P, zero-padded to the t-tile boundary
__global__ __launch_bounds__(256) void attn_softmax(const float* __restrict__ scores,
    u16* __restrict__ p) {
  const int t = blockIdx.x, tid = threadIdx.x;
  const float* row = scores + ((size_t)blockIdx.y * 1024 + t) * 1024;
  u16* prow = p + ((size_t)blockIdx.y * 1024 + t) * 1024;
  const int n = t + 1;
  const int send = ((t >> 7) + 1) << 7;
  __shared__ float sred[4];
  float mx = -1e30f;
  for (int i = tid; i < n; i += 256) mx = fmaxf(mx, row[i]);
#pragma unroll
  for (int off = 32; off >= 1; off >>= 1) mx = fmaxf(mx, __shfl_down(mx, off));
  if ((tid & 63) == 0) sred[tid >> 6] = mx;
  __syncthreads();
  mx = fmaxf(fmaxf(sred[0], sred[1]), fmaxf(sred[2], sred[3]));
  __syncthreads();
  float sm = 0.f;
  for (int i = tid; i < n; i += 256) sm += __expf(row[i] - mx);
  sm = block_sum(sm, sred);
  const float inv = 1.f / sm;
  for (int i = tid; i < send; i += 256) {
    float v = (i < n) ? __expf(row[i] - mx) * inv : 0.f;
    prow[i] = f2b(v);
  }
}

// vT[bh][hd][s] = v part of qkv  (so PV's B-operand is K-contiguous)
__global__ __launch_bounds__(256) void gather_vT(const u16* __restrict__ qkv,
    u16* __restrict__ vT) {
  const int st = blockIdx.x;   // 16 tiles of 64 s
  const int bh = blockIdx.y;   // 32
  const int b = bh >> 4, h = bh & 15;
  __shared__ u16 tile[64][80];
  const int tid = threadIdx.x;
#pragma unroll
  for (int i = 0; i < 2; ++i) {
    int c = i * 256 + tid;
    int sl = c >> 3, h8 = c & 7;
    *(s16x8*)&tile[sl][h8 * 8] =
        *(const s16x8*)(qkv + (size_t)(b * 1024 + st * 64 + sl) * 3072 + 2048 + h * 64 + h8 * 8);
  }
  __syncthreads();
#pragma unroll
  for (int i = 0; i < 2; ++i) {
    int c = i * 256 + tid;
    int hd = c >> 3, s8 = c & 7;
    s16x8 o;
#pragma unroll
    for (int j = 0; j < 8; ++j) o[j] = (short)tile[s8 * 8 + j][hd];
    *(s16x8*)(vT + ((size_t)bh * 64 + hd) * 1024 + st * 64 + s8 * 8) = o;
  }
}

// x[b, t, h*64+hd] += sum_s P[t,s] * v[s,hd]
__global__ __launch_bounds__(256) void attn_pv(const u16* __restrict__ p,
    const u16* __restrict__ vT, float* __restrict__ x, int bh0) {
  const int tt = blockIdx.x;
  const int bh = bh0 + blockIdx.y;
  const int b = bh >> 4, h = bh & 15;
  __shared__ __align__(128) char lds[2 * 12288];
  const u16* A = p + ((size_t)blockIdx.y * 1024 + tt * 128) * 1024;
  const u16* B = vT + (size_t)bh * 65536;
  const f32x4 vz = {0.f, 0.f, 0.f, 0.f};
  f32x4 acc[2][4];
#pragma unroll
  for (int i = 0; i < 2; ++i)
#pragma unroll
    for (int j = 0; j < 4; ++j) acc[i][j] = vz;
  gemm_core<2, 4, 4, 1, 64>(A, 1024, B, 1024, (tt + 1) * 4, lds, acc);
  const int tid = threadIdx.x, lane = tid & 63, w = tid >> 6;
  const int fr = lane & 15, k8 = lane >> 4;
#pragma unroll
  for (int mi = 0; mi < 2; ++mi)
#pragma unroll
    for (int ni = 0; ni < 4; ++ni) {
      const int hd = ni * 16 + fr;
#pragma unroll
      for (int j = 0; j < 4; ++j) {
        const int tl = w * 32 + mi * 16 + k8 * 4 + j;
        x[(size_t)(b * 1024 + tt * 128 + tl) * 1024 + h * 64 + hd] += acc[mi][ni][j];
      }
    }
}

// in-place softmax over V=32000 (online max/sum, then normalize)
__global__ __launch_bounds__(256) void softmax_v(float* __restrict__ logits) {
  const int row = blockIdx.x, tid = threadIdx.x;
  float* lr = logits + (size_t)row * 32000;
  float mx = -1e30f, sm = 0.f;
  for (int i = tid; i < 32000; i += 256) {
    float v = lr[i];
    float m2 = fmaxf(mx, v);
    sm = sm * __expf(mx - m2) + __expf(v - m2);
    mx = m2;
  }
  __shared__ float smx[4], ssm[4];
#pragma unroll
  for (int off = 32; off >= 1; off >>= 1) {
    float om = __shfl_down(mx, off), os = __shfl_down(sm, off);
    float m2 = fmaxf(mx, om);
    sm = sm * __expf(mx - m2) + os * __expf(om - m2);
    mx = m2;
  }
  if ((tid & 63) == 0) { smx[tid >> 6] = mx; ssm[tid >> 6] = sm; }
  __syncthreads();
  const float M = fmaxf(fmaxf(smx[0], smx[1]), fmaxf(smx[2], smx[3]));
  const float S = ssm[0] * __expf(smx[0] - M) + ssm[1] * __expf(smx[1] - M) +
                  ssm[2] * __expf(smx[2] - M) + ssm[3] * __expf(smx[3] - M);
  const float inv = 1.f / S;
  for (int i = tid; i < 32000; i += 256) lr[i] = __expf(lr[i] - M) * inv;
}

// ---------------- host ----------------

extern "C" void kernel_launch(void* const* d_in, const int* in_sizes, int n_in,
                              void* d_out, int out_size, void* d_ws, size_t ws_size,
                              hipStream_t stream) {
  const int*   ctx   = (const int*)d_in[0];
  const float* tok   = (const float*)d_in[1];
  const float* pos   = (const float*)d_in[2];
  const float* wq    = (const float*)d_in[3];
  const float* wk    = (const float*)d_in[4];
  const float* wv    = (const float*)d_in[5];
  const float* ln1_s = (const float*)d_in[6];
  const float* ln1_b = (const float*)d_in[7];
  const float* ln2_s = (const float*)d_in[8];
  const float* ln2_b = (const float*)d_in[9];
  const float* fw1   = (const float*)d_in[10];
  const float* fb1   = (const float*)d_in[11];
  const float* fw2   = (const float*)d_in[12];
  const float* fb2   = (const float*)d_in[13];
  const float* lnf_s = (const float*)d_in[14];
  const float* lnf_b = (const float*)d_in[15];
  const float* wp    = (const float*)d_in[16];
  const float* bp    = (const float*)d_in[17];
  float* out = (float*)d_out;

  // workspace carve-up (~326 MB total)
  char* ws = (char*)d_ws;
  size_t o = 0;
  auto get = [&](size_t bytes) {
    char* r = ws + o;
    o += (bytes + 255) & ~(size_t)255;
    return r;
  };
  u16*   wqkvT = (u16*)get(12ULL * 3072 * 1024 * 2);   // per layer [3072 out][1024 in]
  u16*   wf1T  = (u16*)get(12ULL * 1024 * 1024 * 2);
  u16*   wf2T  = (u16*)get(12ULL * 1024 * 1024 * 2);
  u16*   wpT   = (u16*)get(32000ULL * 1024 * 2);
  float* x     = (float*)get(2048ULL * 1024 * 4);
  u16*   h     = (u16*)get(2048ULL * 1024 * 2);
  u16*   qkvb  = (u16*)get(2048ULL * 3072 * 2);
  u16*   vT    = (u16*)get(32ULL * 64 * 1024 * 2);
  u16*   f1b   = (u16*)get(2048ULL * 1024 * 2);
  float* sc    = (float*)get(16ULL * 1024 * 1024 * 4); // scores, 16 bh-chunk
  u16*   pbuf  = (u16*)get(16ULL * 1024 * 1024 * 2);

  // embeddings + one-time weight transposes (fp32 -> bf16 B^T layout)
  embed_kernel<<<2048, 256, 0, stream>>>(ctx, tok, pos, x);
  transpose_qkv<<<dim3(32, 32, 36), 256, 0, stream>>>(wq, wk, wv, wqkvT);
  transpose_cvt<<<dim3(32, 32, 12), 256, 0, stream>>>(fw1, wf1T, 1024, 1048576, 1048576);
  transpose_cvt<<<dim3(32, 32, 12), 256, 0, stream>>>(fw2, wf2T, 1024, 1048576, 1048576);
  transpose_cvt<<<dim3(1000, 32, 1), 256, 0, stream>>>(wp, wpT, 32000, 0, 0);

  for (int l = 0; l < 12; ++l) {
    layernorm_bf16<<<2048, 256, 0, stream>>>(x, ln1_s + l * 1024, ln1_b + l * 1024, h);
    gemm_bt<false, false, false, true><<<dim3(24, 16), 256, 0, stream>>>(
        h, 1024, wqkvT + (size_t)l * 3145728, 1024, nullptr, nullptr, qkvb, 3072, 32);
    gather_vT<<<dim3(16, 32), 256, 0, stream>>>(qkvb, vT);
    for (int c0 = 0; c0 < 2; ++c0) {  // 2 chunks of 16 (b,h) pairs to bound ws
      attn_scores<<<dim3(8, 8, 16), 256, 0, stream>>>(qkvb, sc, c0 * 16);
      attn_softmax<<<dim3(1024, 16), 256, 0, stream>>>(sc, pbuf);
      attn_pv<<<dim3(8, 16), 256, 0, stream>>>(pbuf, vT, x, c0 * 16);
    }
    layernorm_bf16<<<2048, 256, 0, stream>>>(x, ln2_s + l * 1024, ln2_b + l * 1024, h);
    gemm_bt<true, true, false, true><<<dim3(8, 16), 256, 0, stream>>>(
        h, 1024, wf1T + (size_t)l * 1048576, 1024, fb1 + l * 1024, nullptr, f1b, 1024, 32);
    gemm_bt<true, false, true, false><<<dim3(8, 16), 256, 0, stream>>>(
        f1b, 1024, wf2T + (size_t)l * 1048576, 1024, fb2 + l * 1024, x, x, 1024, 32);
  }

  layernorm_bf16<<<2048, 256, 0, stream>>>(x, lnf_s, lnf_b, h);
  gemm_bt<true, false, false, false><<<dim3(250, 16), 256, 0, stream>>>(
      h, 1024, wpT, 1024, bp, nullptr, out, 32000, 32);
  softmax_v<<<2048, 256, 0, stream>>>(out);
}

// Round 3
// 2427.006 us; speedup vs baseline: 1.3531x; 1.3531x over previous
//
#include <hip/hip_runtime.h>
#include <hip/hip_bf16.h>

typedef unsigned short u16;
typedef float f32x4 __attribute__((ext_vector_type(4)));
typedef __bf16 bf16x8 __attribute__((ext_vector_type(8)));
typedef short s16x8 __attribute__((ext_vector_type(8)));

// ---------------- helpers ----------------

__device__ __forceinline__ u16 f2b(float f) {
  union { __hip_bfloat16 h; u16 u; } c;
  c.h = __float2bfloat16(f);
  return c.u;
}

__device__ __forceinline__ void gload16(const void* g, void* l) {
  __builtin_amdgcn_global_load_lds(
      (const __attribute__((address_space(1))) unsigned int*)g,
      (__attribute__((address_space(3))) unsigned int*)l, 16, 0, 0);
}

__device__ __forceinline__ float block_sum(float v, float* sred) {
  const int tid = threadIdx.x;
#pragma unroll
  for (int off = 32; off >= 1; off >>= 1) v += __shfl_down(v, off);
  if ((tid & 63) == 0) sred[tid >> 6] = v;
  __syncthreads();
  float r = sred[0] + sred[1] + sred[2] + sred[3];
  __syncthreads();
  return r;
}

__device__ __forceinline__ f32x4 fmax4(f32x4 a, f32x4 b) {
  f32x4 r;
  r[0] = fmaxf(a[0], b[0]); r[1] = fmaxf(a[1], b[1]);
  r[2] = fmaxf(a[2], b[2]); r[3] = fmaxf(a[3], b[3]);
  return r;
}

// ---------------- GEMM core (64 B rows = 32 bf16 K-slab) ----------------
// LDS tile row-major [ROWS][32] bf16, 16B slots XOR-swizzled slot'=k8^((row>>1)&3).
// Swizzle applied on the GLOBAL source (global_load_lds dest must be linear),
// identical XOR on the ds_read side.

template<int ROWS>
__device__ __forceinline__ void stage_tile(const u16* g, int ld, char* ldsb, int tid) {
#pragma unroll
  for (int i = 0; i < ROWS / 64; ++i) {
    int c = i * 256 + tid;
    int row = c >> 2;
    int k8 = (c & 3) ^ ((row >> 1) & 3);
    gload16(g + (size_t)row * ld + k8 * 8, ldsb + i * 4096 + (tid & 192) * 16);
  }
}

template<int MI, int NI, int WCN>
__device__ __forceinline__ void compute_tile(const char* lA, const char* lB, f32x4 (&acc)[MI][NI]) {
  const int tid = threadIdx.x;
  const int lane = tid & 63;
  const int w = tid >> 6;
  const int wr = w / WCN, wc = w % WCN;
  const int fr = lane & 15, k8 = lane >> 4;
  bf16x8 a[MI], b[NI];
#pragma unroll
  for (int mi = 0; mi < MI; ++mi) {
    int row = wr * (MI * 16) + mi * 16 + fr;
    a[mi] = *(const bf16x8*)(lA + row * 64 + ((k8 ^ ((row >> 1) & 3)) << 4));
  }
#pragma unroll
  for (int ni = 0; ni < NI; ++ni) {
    int row = wc * (NI * 16) + ni * 16 + fr;
    b[ni] = *(const bf16x8*)(lB + row * 64 + ((k8 ^ ((row >> 1) & 3)) << 4));
  }
#pragma unroll
  for (int mi = 0; mi < MI; ++mi)
#pragma unroll
    for (int ni = 0; ni < NI; ++ni)
      acc[mi][ni] = __builtin_amdgcn_mfma_f32_16x16x32_bf16(a[mi], b[ni], acc[mi][ni], 0, 0, 0);
}

template<int MI, int NI, int WRN, int WCN, int BMT, int BNT>
__device__ __forceinline__ void gemm_core(const u16* A, int lda, const u16* B, int ldb,
                                          int nkt, char* lds, f32x4 (&acc)[MI][NI]) {
  const int tid = threadIdx.x;
  const int bufSz = BMT * 64 + BNT * 64;
  stage_tile<BMT>(A, lda, lds, tid);
  stage_tile<BNT>(B, ldb, lds + BMT * 64, tid);
  __syncthreads();
  int cur = 0;
  for (int kt = 0; kt < nkt; ++kt) {
    if (kt + 1 < nkt) {
      char* nb = lds + (cur ^ 1) * bufSz;
      stage_tile<BMT>(A + (size_t)(kt + 1) * 32, lda, nb, tid);
      stage_tile<BNT>(B + (size_t)(kt + 1) * 32, ldb, nb + BMT * 64, tid);
    }
    char* cb = lds + cur * bufSz;
    compute_tile<MI, NI, WCN>(cb, cb + BMT * 64, acc);
    __syncthreads();
    cur ^= 1;
  }
}

// ---------------- flash-attn staging (128 B rows = 64 bf16) ----------------
// slot' = slot ^ (row&7): conflict-free ds_read_b128 of [row][64] tiles.

template<int ROWS>
__device__ __forceinline__ void stage64(const u16* g, int ld, char* ldsb, int tid) {
#pragma unroll
  for (int i = 0; i < ROWS / 32; ++i) {
    int c = i * 256 + tid;
    int row = c >> 3;
    int slot = (c & 7) ^ (row & 7);
    gload16(g + (size_t)row * ld + slot * 8, ldsb + i * 4096 + (tid & 192) * 16);
  }
}

__device__ __forceinline__ bf16x8 ldread64(const char* base, int row, int slot) {
  return *(const bf16x8*)(base + row * 128 + ((slot ^ (row & 7)) << 4));
}

// ---------------- kernels ----------------

__global__ __launch_bounds__(256) void embed_kernel(const int* __restrict__ ctx,
    const float* __restrict__ tok, const float* __restrict__ pos, float* __restrict__ x) {
  const int row = blockIdx.x, tid = threadIdx.x;
  const int t = row & 1023;
  const int id = ctx[row];
  float4 a = ((const float4*)(tok + (size_t)id * 1024))[tid];
  float4 p = ((const float4*)(pos + (size_t)t * 1024))[tid];
  a.x += p.x; a.y += p.y; a.z += p.z; a.w += p.w;
  ((float4*)(x + (size_t)row * 1024))[tid] = a;
}

__global__ __launch_bounds__(256) void layernorm_bf16(const float* __restrict__ x,
    const float* __restrict__ sc, const float* __restrict__ bi, u16* __restrict__ h) {
  __shared__ float sred[4];
  const int row = blockIdx.x, tid = threadIdx.x;
  const float4 v = ((const float4*)(x + (size_t)row * 1024))[tid];
  float mean = block_sum(v.x + v.y + v.z + v.w, sred) * (1.f / 1024.f);
  const float dx = v.x - mean, dy = v.y - mean, dz = v.z - mean, dw = v.w - mean;
  float var = block_sum(dx * dx + dy * dy + dz * dz + dw * dw, sred) * (1.f / 1024.f);
  const float rs = rsqrtf(var + 1e-5f);
  const float4 s4 = ((const float4*)sc)[tid];
  const float4 b4 = ((const float4*)bi)[tid];
  ushort4 o;
  o.x = f2b(dx * rs * s4.x + b4.x);
  o.y = f2b(dy * rs * s4.y + b4.y);
  o.z = f2b(dz * rs * s4.z + b4.z);
  o.w = f2b(dw * rs * s4.w + b4.w);
  ((ushort4*)(h + (size_t)row * 1024))[tid] = o;
}

__device__ __forceinline__ void transpose_body(const float* __restrict__ src,
                                               u16* __restrict__ dst, int N) {
  __shared__ float tile[32][33];
  const int tid = threadIdx.x;
  const int tx = tid & 31, ty = tid >> 5;
  const int kt = blockIdx.y * 32, nt = blockIdx.x * 32;
#pragma unroll
  for (int i = 0; i < 4; ++i) {
    int r = ty + i * 8;
    tile[r][tx] = src[(size_t)(kt + r) * N + nt + tx];
  }
  __syncthreads();
#pragma unroll
  for (int i = 0; i < 4; ++i) {
    int r = ty + i * 8;
    dst[(size_t)(nt + r) * 1024 + kt + tx] = f2b(tile[tx][r]);
  }
}

__global__ __launch_bounds__(256) void transpose_cvt(const float* __restrict__ src,
    u16* __restrict__ dst, int N, size_t srcStride, size_t dstStride) {
  transpose_body(src + blockIdx.z * srcStride, dst + blockIdx.z * dstStride, N);
}

__global__ __launch_bounds__(256) void transpose_qkv(const float* __restrict__ wq,
    const float* __restrict__ wk, const float* __restrict__ wv, u16* __restrict__ dst) {
  const int z = blockIdx.z, l = z / 3, which = z - l * 3;
  const float* src = (which == 0 ? wq : (which == 1 ? wk : wv)) + (size_t)l * 1048576;
  u16* d = dst + (size_t)l * 3145728 + (size_t)which * 1048576;
  transpose_body(src, d, 1024);
}

// generic C = A@Bt^T. Tile = (WRN*MI*16) x (WCN*NI*16). XSWAP: grid.x = M tiles.
template<int MI, int NI, int WRN, int WCN, bool BIAS, bool RELU, bool RESID, bool OUTBF, bool XSWAP>
__global__ __launch_bounds__(256) void gemm_bt(const u16* __restrict__ A, int lda,
    const u16* __restrict__ Bt, int ldb, const float* __restrict__ bias,
    const float* __restrict__ resid, void* __restrict__ out, int ldc, int nkt) {
  constexpr int BMT = WRN * MI * 16;
  constexpr int BNT = WCN * NI * 16;
  __shared__ __align__(128) char lds[2 * (BMT * 64 + BNT * 64)];
  const int bmi = XSWAP ? blockIdx.x : blockIdx.y;
  const int bni = XSWAP ? blockIdx.y : blockIdx.x;
  const size_t bm = (size_t)bmi * BMT, bn = (size_t)bni * BNT;
  const f32x4 vz = {0.f, 0.f, 0.f, 0.f};
  f32x4 acc[MI][NI];
#pragma unroll
  for (int i = 0; i < MI; ++i)
#pragma unroll
    for (int j = 0; j < NI; ++j) acc[i][j] = vz;
  gemm_core<MI, NI, WRN, WCN, BMT, BNT>(A + bm * lda, lda, Bt + bn * ldb, ldb, nkt, lds, acc);
  const int tid = threadIdx.x, lane = tid & 63, w = tid >> 6;
  const int wr = w / WCN, wc = w % WCN, fr = lane & 15, k8 = lane >> 4;
#pragma unroll
  for (int mi = 0; mi < MI; ++mi)
#pragma unroll
    for (int ni = 0; ni < NI; ++ni) {
      const size_t c = bn + wc * (NI * 16) + ni * 16 + fr;
      const float bv = BIAS ? bias[c] : 0.f;
#pragma unroll
      for (int j = 0; j < 4; ++j) {
        const size_t r = bm + wr * (MI * 16) + mi * 16 + k8 * 4 + j;
        float v = acc[mi][ni][j] + bv;
        if (RELU) v = fmaxf(v, 0.f);
        if (RESID) v += resid[r * (size_t)ldc + c];
        if (OUTBF) ((u16*)out)[r * (size_t)ldc + c] = f2b(v);
        else       ((float*)out)[r * (size_t)ldc + c] = v;
      }
    }
}

// vT[bh][hd][s] = v part of qkv
__global__ __launch_bounds__(256) void gather_vT(const u16* __restrict__ qkv,
    u16* __restrict__ vT) {
  const int st = blockIdx.x;
  const int bh = blockIdx.y;
  const int b = bh >> 4, h = bh & 15;
  __shared__ u16 tile[64][80];
  const int tid = threadIdx.x;
#pragma unroll
  for (int i = 0; i < 2; ++i) {
    int c = i * 256 + tid;
    int sl = c >> 3, h8 = c & 7;
    *(s16x8*)&tile[sl][h8 * 8] =
        *(const s16x8*)(qkv + (size_t)(b * 1024 + st * 64 + sl) * 3072 + 2048 + h * 64 + h8 * 8);
  }
  __syncthreads();
#pragma unroll
  for (int i = 0; i < 2; ++i) {
    int c = i * 256 + tid;
    int hd = c >> 3, s8 = c & 7;
    s16x8 o;
#pragma unroll
    for (int j = 0; j < 8; ++j) o[j] = (short)tile[s8 * 8 + j][hd];
    *(s16x8*)(vT + ((size_t)bh * 64 + hd) * 1024 + st * 64 + s8 * 8) = o;
  }
}

// fused flash attention: per (t-tile of 128, b*h). 4 waves x 32 t-rows.
// S/O in MFMA acc layout: row t = mi*16 + (lane>>4)*4 + j, col = lane&15 (+16*ni).
__global__ __launch_bounds__(256) void attn_flash(const u16* __restrict__ qkv,
    const u16* __restrict__ vT, float* __restrict__ x) {
  const int tt = blockIdx.x;
  const int bh = blockIdx.y;
  const int b = bh >> 4, h = bh & 15;
  __shared__ __align__(128) char lds[65536];
  char* Qs = lds;                       // [128][64]
  char* Ks = lds + 16384;               // 2 x [64][64]
  char* Vs = lds + 32768;               // 2 x [64][64]
  const int tid = threadIdx.x, lane = tid & 63, w = tid >> 6;
  const int fr = lane & 15, k8 = lane >> 4;
  char* Pw = lds + 49152 + w * 4096;    // per-wave [32][64]
  const u16* qbase = qkv + (size_t)(b * 1024 + tt * 128) * 3072 + h * 64;
  const u16* kbase = qkv + (size_t)(b * 1024) * 3072 + 1024 + h * 64;
  const u16* vbase = vT + (size_t)bh * 65536;

  stage64<128>(qbase, 3072, Qs, tid);
  stage64<64>(kbase, 3072, Ks, tid);
  stage64<64>(vbase, 1024, Vs, tid);
  __syncthreads();

  bf16x8 aq[2][2];
#pragma unroll
  for (int mi = 0; mi < 2; ++mi)
#pragma unroll
    for (int kk = 0; kk < 2; ++kk)
      aq[mi][kk] = ldread64(Qs, w * 32 + mi * 16 + fr, kk * 4 + k8);

  const f32x4 vz = {0.f, 0.f, 0.f, 0.f};
  const f32x4 vninf = {-1e30f, -1e30f, -1e30f, -1e30f};
  f32x4 oacc[2][4], m_[2], l_[2];
#pragma unroll
  for (int mi = 0; mi < 2; ++mi) {
    m_[mi] = vninf; l_[mi] = vz;
#pragma unroll
    for (int ni = 0; ni < 4; ++ni) oacc[mi][ni] = vz;
  }

  const int nst = tt * 2 + 2;
  const int t0 = tt * 128 + w * 32;   // wave's first global t-row
  int cur = 0;
  for (int st = 0; st < nst; ++st) {
    if (st + 1 < nst) {
      stage64<64>(kbase + (size_t)(st + 1) * 64 * 3072, 3072, Ks + (cur ^ 1) * 8192, tid);
      stage64<64>(vbase + (st + 1) * 64, 1024, Vs + (cur ^ 1) * 8192, tid);
    }
    if (st * 64 <= t0 + 31) {  // wave-uniform skip of fully-masked tiles
      const char* Kc = Ks + cur * 8192;
      const char* Vc = Vs + cur * 8192;
      f32x4 sacc[2][4];
#pragma unroll
      for (int mi = 0; mi < 2; ++mi)
#pragma unroll
        for (int ni = 0; ni < 4; ++ni) sacc[mi][ni] = vz;
#pragma unroll
      for (int kk = 0; kk < 2; ++kk) {
        bf16x8 bk[4];
#pragma unroll
        for (int ni = 0; ni < 4; ++ni) bk[ni] = ldread64(Kc, ni * 16 + fr, kk * 4 + k8);
#pragma unroll
        for (int mi = 0; mi < 2; ++mi)
#pragma unroll
          for (int ni = 0; ni < 4; ++ni)
            sacc[mi][ni] = __builtin_amdgcn_mfma_f32_16x16x32_bf16(aq[mi][kk], bk[ni], sacc[mi][ni], 0, 0, 0);
      }
      const int sbase = st * 64;
      const bool needMask = (sbase + 63 > t0);
#pragma unroll
      for (int mi = 0; mi < 2; ++mi) {
#pragma unroll
        for (int ni = 0; ni < 4; ++ni) {
          sacc[mi][ni] *= 0.125f;
          if (needMask) {
            const int s = sbase + ni * 16 + fr;
#pragma unroll
            for (int j = 0; j < 4; ++j) {
              const int t = t0 + mi * 16 + k8 * 4 + j;
              if (s > t) sacc[mi][ni][j] = -1e30f;
            }
          }
        }
        f32x4 pm = fmax4(fmax4(sacc[mi][0], sacc[mi][1]), fmax4(sacc[mi][2], sacc[mi][3]));
#pragma unroll
        for (int msk = 1; msk <= 8; msk <<= 1) {
#pragma unroll
          for (int j = 0; j < 4; ++j) pm[j] = fmaxf(pm[j], __shfl_xor(pm[j], msk));
        }
        const f32x4 mn = fmax4(m_[mi], pm);
        f32x4 alpha, rs = vz;
#pragma unroll
        for (int j = 0; j < 4; ++j) alpha[j] = __expf(m_[mi][j] - mn[j]);
#pragma unroll
        for (int ni = 0; ni < 4; ++ni) {
#pragma unroll
          for (int j = 0; j < 4; ++j) {
            const float p = __expf(sacc[mi][ni][j] - mn[j]);
            rs[j] += p;
            const int t_loc = mi * 16 + k8 * 4 + j;
            const int s_loc = ni * 16 + fr;
            *(u16*)(Pw + t_loc * 128 + (((s_loc >> 3) ^ (t_loc & 7)) << 4) + (s_loc & 7) * 2) = f2b(p);
          }
        }
#pragma unroll
        for (int msk = 1; msk <= 8; msk <<= 1) {
#pragma unroll
          for (int j = 0; j < 4; ++j) rs[j] += __shfl_xor(rs[j], msk);
        }
        m_[mi] = mn;
#pragma unroll
        for (int j = 0; j < 4; ++j) l_[mi][j] = l_[mi][j] * alpha[j] + rs[j];
#pragma unroll
        for (int ni = 0; ni < 4; ++ni) oacc[mi][ni] *= alpha;
      }
      // PV: A = P (per-wave LDS), B = V^T
#pragma unroll
      for (int kk = 0; kk < 2; ++kk) {
        bf16x8 ap[2], bv[4];
#pragma unroll
        for (int mi = 0; mi < 2; ++mi) ap[mi] = ldread64(Pw, mi * 16 + fr, kk * 4 + k8);
#pragma unroll
        for (int ni = 0; ni < 4; ++ni) bv[ni] = ldread64(Vc, ni * 16 + fr, kk * 4 + k8);
#pragma unroll
        for (int mi = 0; mi < 2; ++mi)
#pragma unroll
          for (int ni = 0; ni < 4; ++ni)
            oacc[mi][ni] = __builtin_amdgcn_mfma_f32_16x16x32_bf16(ap[mi], bv[ni], oacc[mi][ni], 0, 0, 0);
      }
    }
    __syncthreads();
    cur ^= 1;
  }
  // epilogue: O /= l, accumulate into residual x
#pragma unroll
  for (int mi = 0; mi < 2; ++mi) {
    f32x4 invl;
#pragma unroll
    for (int j = 0; j < 4; ++j) invl[j] = 1.f / l_[mi][j];
#pragma unroll
    for (int ni = 0; ni < 4; ++ni) {
      const int hd = ni * 16 + fr;
#pragma unroll
      for (int j = 0; j < 4; ++j) {
        const int t = tt * 128 + w * 32 + mi * 16 + k8 * 4 + j;
        x[(size_t)(b * 1024 + t) * 1024 + h * 64 + hd] += oacc[mi][ni][j] * invl[j];
      }
    }
  }
}

// in-place softmax over V=32000, float4-vectorized
__global__ __launch_bounds__(256) void softmax_v(float* __restrict__ logits) {
  const int row = blockIdx.x, tid = threadIdx.x;
  float* lr = logits + (size_t)row * 32000;
  const float4* lr4 = (const float4*)lr;
  float mx = -1e30f, sm = 0.f;
  for (int i = tid; i < 8000; i += 256) {
    const float4 v = lr4[i];
    float vm = fmaxf(fmaxf(v.x, v.y), fmaxf(v.z, v.w));
    float m2 = fmaxf(mx, vm);
    sm = sm * __expf(mx - m2) + __expf(v.x - m2) + __expf(v.y - m2) +
         __expf(v.z - m2) + __expf(v.w - m2);
    mx = m2;
  }
  __shared__ float smx[4], ssm[4];
#pragma unroll
  for (int off = 32; off >= 1; off >>= 1) {
    float om = __shfl_down(mx, off), os = __shfl_down(sm, off);
    float m2 = fmaxf(mx, om);
    sm = sm * __expf(mx - m2) + os * __expf(om - m2);
    mx = m2;
  }
  if ((tid & 63) == 0) { smx[tid >> 6] = mx; ssm[tid >> 6] = sm; }
  __syncthreads();
  const float M = fmaxf(fmaxf(smx[0], smx[1]), fmaxf(smx[2], smx[3]));
  const float S = ssm[0] * __expf(smx[0] - M) + ssm[1] * __expf(smx[1] - M) +
                  ssm[2] * __expf(smx[2] - M) + ssm[3] * __expf(smx[3] - M);
  const float inv = 1.f / S;
  float4* lw4 = (float4*)lr;
  for (int i = tid; i < 8000; i += 256) {
    float4 v = lw4[i];
    v.x = __expf(v.x - M) * inv; v.y = __expf(v.y - M) * inv;
    v.z = __expf(v.z - M) * inv; v.w = __expf(v.w - M) * inv;
    lw4[i] = v;
  }
}

// ---------------- host ----------------

extern "C" void kernel_launch(void* const* d_in, const int* in_sizes, int n_in,
                              void* d_out, int out_size, void* d_ws, size_t ws_size,
                              hipStream_t stream) {
  const int*   ctx   = (const int*)d_in[0];
  const float* tok   = (const float*)d_in[1];
  const float* pos   = (const float*)d_in[2];
  const float* wq    = (const float*)d_in[3];
  const float* wk    = (const float*)d_in[4];
  const float* wv    = (const float*)d_in[5];
  const float* ln1_s = (const float*)d_in[6];
  const float* ln1_b = (const float*)d_in[7];
  const float* ln2_s = (const float*)d_in[8];
  const float* ln2_b = (const float*)d_in[9];
  const float* fw1   = (const float*)d_in[10];
  const float* fb1   = (const float*)d_in[11];
  const float* fw2   = (const float*)d_in[12];
  const float* fb2   = (const float*)d_in[13];
  const float* lnf_s = (const float*)d_in[14];
  const float* lnf_b = (const float*)d_in[15];
  const float* wp    = (const float*)d_in[16];
  const float* bp    = (const float*)d_in[17];
  float* out = (float*)d_out;

  char* ws = (char*)d_ws;
  size_t o = 0;
  auto get = [&](size_t bytes) {
    char* r = ws + o;
    o += (bytes + 255) & ~(size_t)255;
    return r;
  };
  u16*   wqkvT = (u16*)get(12ULL * 3072 * 1024 * 2);
  u16*   wf1T  = (u16*)get(12ULL * 1024 * 1024 * 2);
  u16*   wf2T  = (u16*)get(12ULL * 1024 * 1024 * 2);
  u16*   wpT   = (u16*)get(32000ULL * 1024 * 2);
  float* x     = (float*)get(2048ULL * 1024 * 4);
  u16*   h     = (u16*)get(2048ULL * 1024 * 2);
  u16*   qkvb  = (u16*)get(2048ULL * 3072 * 2);
  u16*   vT    = (u16*)get(32ULL * 64 * 1024 * 2);
  u16*   f1b   = (u16*)get(2048ULL * 1024 * 2);

  embed_kernel<<<2048, 256, 0, stream>>>(ctx, tok, pos, x);
  transpose_qkv<<<dim3(32, 32, 36), 256, 0, stream>>>(wq, wk, wv, wqkvT);
  transpose_cvt<<<dim3(32, 32, 12), 256, 0, stream>>>(fw1, wf1T, 1024, 1048576, 1048576);
  transpose_cvt<<<dim3(32, 32, 12), 256, 0, stream>>>(fw2, wf2T, 1024, 1048576, 1048576);
  transpose_cvt<<<dim3(1000, 32, 1), 256, 0, stream>>>(wp, wpT, 32000, 0, 0);

  for (int l = 0; l < 12; ++l) {
    layernorm_bf16<<<2048, 256, 0, stream>>>(x, ln1_s + l * 1024, ln1_b + l * 1024, h);
    gemm_bt<4, 4, 2, 2, false, false, false, true, false><<<dim3(24, 16), 256, 0, stream>>>(
        h, 1024, wqkvT + (size_t)l * 3145728, 1024, nullptr, nullptr, qkvb, 3072, 32);
    gather_vT<<<dim3(16, 32), 256, 0, stream>>>(qkvb, vT);
    attn_flash<<<dim3(8, 32), 256, 0, stream>>>(qkvb, vT, x);
    layernorm_bf16<<<2048, 256, 0, stream>>>(x, ln2_s + l * 1024, ln2_b + l * 1024, h);
    gemm_bt<4, 2, 2, 2, true, true, false, true, false><<<dim3(16, 16), 256, 0, stream>>>(
        h, 1024, wf1T + (size_t)l * 1048576, 1024, fb1 + l * 1024, nullptr, f1b, 1024, 32);
    gemm_bt<4, 2, 2, 2, true, false, true, false, false><<<dim3(16, 16), 256, 0, stream>>>(
        f1b, 1024, wf2T + (size_t)l * 1048576, 1024, fb2 + l * 1024, x, x, 1024, 32);
  }

  layernorm_bf16<<<2048, 256, 0, stream>>>(x, lnf_s, lnf_b, h);
  gemm_bt<4, 4, 2, 2, true, false, false, false, true><<<dim3(16, 250), 256, 0, stream>>>(
      h, 1024, wpT, 1024, bp, nullptr, out, 32000, 32);
  softmax_v<<<2048, 256, 0, stream>>>(out);
}

// Round 4
// 2197.858 us; speedup vs baseline: 1.4941x; 1.1043x over previous
//
#include <hip/hip_runtime.h>
#include <hip/hip_bf16.h>

typedef unsigned short u16;
typedef float f32x4 __attribute__((ext_vector_type(4)));
typedef __bf16 bf16x8 __attribute__((ext_vector_type(8)));
typedef short s16x8 __attribute__((ext_vector_type(8)));

// ---------------- helpers ----------------

__device__ __forceinline__ u16 f2b(float f) {
  union { __hip_bfloat16 h; u16 u; } c;
  c.h = __float2bfloat16(f);
  return c.u;
}

__device__ __forceinline__ void gload16(const void* g, void* l) {
  __builtin_amdgcn_global_load_lds(
      (const __attribute__((address_space(1))) unsigned int*)g,
      (__attribute__((address_space(3))) unsigned int*)l, 16, 0, 0);
}

__device__ __forceinline__ float block_sum(float v, float* sred) {
  const int tid = threadIdx.x;
#pragma unroll
  for (int off = 32; off >= 1; off >>= 1) v += __shfl_down(v, off);
  if ((tid & 63) == 0) sred[tid >> 6] = v;
  __syncthreads();
  float r = sred[0] + sred[1] + sred[2] + sred[3];
  __syncthreads();
  return r;
}

__device__ __forceinline__ f32x4 fmax4(f32x4 a, f32x4 b) {
  f32x4 r;
  r[0] = fmaxf(a[0], b[0]); r[1] = fmaxf(a[1], b[1]);
  r[2] = fmaxf(a[2], b[2]); r[3] = fmaxf(a[3], b[3]);
  return r;
}

// ---------------- GEMM core (64 B rows = 32 bf16 K-slab) ----------------
// LDS tile row-major [ROWS][32] bf16, 16B slots XOR-swizzled slot'=k8^((row>>1)&3).
// Swizzle applied on the GLOBAL source (global_load_lds dest must be linear),
// identical XOR on the ds_read side.

template<int ROWS>
__device__ __forceinline__ void stage_tile(const u16* g, int ld, char* ldsb, int tid) {
#pragma unroll
  for (int i = 0; i < ROWS / 64; ++i) {
    int c = i * 256 + tid;
    int row = c >> 2;
    int k8 = (c & 3) ^ ((row >> 1) & 3);
    gload16(g + (size_t)row * ld + k8 * 8, ldsb + i * 4096 + (tid & 192) * 16);
  }
}

template<int MI, int NI, int WCN>
__device__ __forceinline__ void compute_tile(const char* lA, const char* lB, f32x4 (&acc)[MI][NI]) {
  const int tid = threadIdx.x;
  const int lane = tid & 63;
  const int w = tid >> 6;
  const int wr = w / WCN, wc = w % WCN;
  const int fr = lane & 15, k8 = lane >> 4;
  bf16x8 a[MI], b[NI];
#pragma unroll
  for (int mi = 0; mi < MI; ++mi) {
    int row = wr * (MI * 16) + mi * 16 + fr;
    a[mi] = *(const bf16x8*)(lA + row * 64 + ((k8 ^ ((row >> 1) & 3)) << 4));
  }
#pragma unroll
  for (int ni = 0; ni < NI; ++ni) {
    int row = wc * (NI * 16) + ni * 16 + fr;
    b[ni] = *(const bf16x8*)(lB + row * 64 + ((k8 ^ ((row >> 1) & 3)) << 4));
  }
#pragma unroll
  for (int mi = 0; mi < MI; ++mi)
#pragma unroll
    for (int ni = 0; ni < NI; ++ni)
      acc[mi][ni] = __builtin_amdgcn_mfma_f32_16x16x32_bf16(a[mi], b[ni], acc[mi][ni], 0, 0, 0);
}

template<int MI, int NI, int WRN, int WCN, int BMT, int BNT>
__device__ __forceinline__ void gemm_core(const u16* A, int lda, const u16* B, int ldb,
                                          int nkt, char* lds, f32x4 (&acc)[MI][NI]) {
  const int tid = threadIdx.x;
  const int bufSz = BMT * 64 + BNT * 64;
  stage_tile<BMT>(A, lda, lds, tid);
  stage_tile<BNT>(B, ldb, lds + BMT * 64, tid);
  __syncthreads();
  int cur = 0;
  for (int kt = 0; kt < nkt; ++kt) {
    if (kt + 1 < nkt) {
      char* nb = lds + (cur ^ 1) * bufSz;
      stage_tile<BMT>(A + (size_t)(kt + 1) * 32, lda, nb, tid);
      stage_tile<BNT>(B + (size_t)(kt + 1) * 32, ldb, nb + BMT * 64, tid);
    }
    char* cb = lds + cur * bufSz;
    compute_tile<MI, NI, WCN>(cb, cb + BMT * 64, acc);
    __syncthreads();
    cur ^= 1;
  }
}

// ---------------- flash-attn staging (128 B rows = 64 bf16) ----------------
// slot' = slot ^ (row&7): conflict-free ds_read_b128 of [row][64] tiles.

template<int ROWS>
__device__ __forceinline__ void stage64(const u16* g, int ld, char* ldsb, int tid) {
#pragma unroll
  for (int i = 0; i < ROWS / 32; ++i) {
    int c = i * 256 + tid;
    int row = c >> 3;
    int slot = (c & 7) ^ (row & 7);
    gload16(g + (size_t)row * ld + slot * 8, ldsb + i * 4096 + (tid & 192) * 16);
  }
}

__device__ __forceinline__ bf16x8 ldread64(const char* base, int row, int slot) {
  return *(const bf16x8*)(base + row * 128 + ((slot ^ (row & 7)) << 4));
}

// ---------------- kernels ----------------

__global__ __launch_bounds__(256) void embed_kernel(const int* __restrict__ ctx,
    const float* __restrict__ tok, const float* __restrict__ pos, float* __restrict__ x) {
  const int row = blockIdx.x, tid = threadIdx.x;
  const int t = row & 1023;
  const int id = ctx[row];
  float4 a = ((const float4*)(tok + (size_t)id * 1024))[tid];
  float4 p = ((const float4*)(pos + (size_t)t * 1024))[tid];
  a.x += p.x; a.y += p.y; a.z += p.z; a.w += p.w;
  ((float4*)(x + (size_t)row * 1024))[tid] = a;
}

__global__ __launch_bounds__(256) void layernorm_bf16(const float* __restrict__ x,
    const float* __restrict__ sc, const float* __restrict__ bi, u16* __restrict__ h) {
  __shared__ float sred[4];
  const int row = blockIdx.x, tid = threadIdx.x;
  const float4 v = ((const float4*)(x + (size_t)row * 1024))[tid];
  float mean = block_sum(v.x + v.y + v.z + v.w, sred) * (1.f / 1024.f);
  const float dx = v.x - mean, dy = v.y - mean, dz = v.z - mean, dw = v.w - mean;
  float var = block_sum(dx * dx + dy * dy + dz * dz + dw * dw, sred) * (1.f / 1024.f);
  const float rs = rsqrtf(var + 1e-5f);
  const float4 s4 = ((const float4*)sc)[tid];
  const float4 b4 = ((const float4*)bi)[tid];
  ushort4 o;
  o.x = f2b(dx * rs * s4.x + b4.x);
  o.y = f2b(dy * rs * s4.y + b4.y);
  o.z = f2b(dz * rs * s4.z + b4.z);
  o.w = f2b(dw * rs * s4.w + b4.w);
  ((ushort4*)(h + (size_t)row * 1024))[tid] = o;
}

__device__ __forceinline__ void transpose_body(const float* __restrict__ src,
                                               u16* __restrict__ dst, int N) {
  __shared__ float tile[32][33];
  const int tid = threadIdx.x;
  const int tx = tid & 31, ty = tid >> 5;
  const int kt = blockIdx.y * 32, nt = blockIdx.x * 32;
#pragma unroll
  for (int i = 0; i < 4; ++i) {
    int r = ty + i * 8;
    tile[r][tx] = src[(size_t)(kt + r) * N + nt + tx];
  }
  __syncthreads();
#pragma unroll
  for (int i = 0; i < 4; ++i) {
    int r = ty + i * 8;
    dst[(size_t)(nt + r) * 1024 + kt + tx] = f2b(tile[tx][r]);
  }
}

__global__ __launch_bounds__(256) void transpose_cvt(const float* __restrict__ src,
    u16* __restrict__ dst, int N, size_t srcStride, size_t dstStride) {
  transpose_body(src + blockIdx.z * srcStride, dst + blockIdx.z * dstStride, N);
}

__global__ __launch_bounds__(256) void transpose_qkv(const float* __restrict__ wq,
    const float* __restrict__ wk, const float* __restrict__ wv, u16* __restrict__ dst) {
  const int z = blockIdx.z, l = z / 3, which = z - l * 3;
  const float* src = (which == 0 ? wq : (which == 1 ? wk : wv)) + (size_t)l * 1048576;
  u16* d = dst + (size_t)l * 3145728 + (size_t)which * 1048576;
  transpose_body(src, d, 1024);
}

// generic C = A@Bt^T. Tile = (WRN*MI*16) x (WCN*NI*16). XSWAP: grid.x = M tiles.
// SWIZ>0: 1-D grid of 8*SWIZ blocks; v'=(v%8)*SWIZ+v/8, bni=v'/16, bmi=v'%16
// (n-major per XCD -> each B-panel fetched by exactly one XCD's L2).
template<int MI, int NI, int WRN, int WCN, bool BIAS, bool RELU, bool RESID, bool OUTBF,
         bool XSWAP, int SWIZ>
__global__ __launch_bounds__(256) void gemm_bt(const u16* __restrict__ A, int lda,
    const u16* __restrict__ Bt, int ldb, const float* __restrict__ bias,
    const float* __restrict__ resid, void* __restrict__ out, int ldc, int nkt) {
  constexpr int BMT = WRN * MI * 16;
  constexpr int BNT = WCN * NI * 16;
  __shared__ __align__(128) char lds[2 * (BMT * 64 + BNT * 64)];
  int bmi, bni;
  if (SWIZ > 0) {
    const int v = blockIdx.x;
    const int vp = (v & 7) * SWIZ + (v >> 3);
    bni = vp >> 4;
    bmi = vp & 15;
  } else {
    bmi = XSWAP ? blockIdx.x : blockIdx.y;
    bni = XSWAP ? blockIdx.y : blockIdx.x;
  }
  const size_t bm = (size_t)bmi * BMT, bn = (size_t)bni * BNT;
  const f32x4 vz = {0.f, 0.f, 0.f, 0.f};
  f32x4 acc[MI][NI];
#pragma unroll
  for (int i = 0; i < MI; ++i)
#pragma unroll
    for (int j = 0; j < NI; ++j) acc[i][j] = vz;
  gemm_core<MI, NI, WRN, WCN, BMT, BNT>(A + bm * lda, lda, Bt + bn * ldb, ldb, nkt, lds, acc);
  const int tid = threadIdx.x, lane = tid & 63, w = tid >> 6;
  const int wr = w / WCN, wc = w % WCN, fr = lane & 15, k8 = lane >> 4;
#pragma unroll
  for (int mi = 0; mi < MI; ++mi)
#pragma unroll
    for (int ni = 0; ni < NI; ++ni) {
      const size_t c = bn + wc * (NI * 16) + ni * 16 + fr;
      const float bv = BIAS ? bias[c] : 0.f;
#pragma unroll
      for (int j = 0; j < 4; ++j) {
        const size_t r = bm + wr * (MI * 16) + mi * 16 + k8 * 4 + j;
        float v = acc[mi][ni][j] + bv;
        if (RELU) v = fmaxf(v, 0.f);
        if (RESID) v += resid[r * (size_t)ldc + c];
        if (OUTBF) ((u16*)out)[r * (size_t)ldc + c] = f2b(v);
        else       ((float*)out)[r * (size_t)ldc + c] = v;
      }
    }
}

// vT[bh][hd][s] = v part of qkv
__global__ __launch_bounds__(256) void gather_vT(const u16* __restrict__ qkv,
    u16* __restrict__ vT) {
  const int st = blockIdx.x;
  const int bh = blockIdx.y;
  const int b = bh >> 4, h = bh & 15;
  __shared__ u16 tile[64][80];
  const int tid = threadIdx.x;
#pragma unroll
  for (int i = 0; i < 2; ++i) {
    int c = i * 256 + tid;
    int sl = c >> 3, h8 = c & 7;
    *(s16x8*)&tile[sl][h8 * 8] =
        *(const s16x8*)(qkv + (size_t)(b * 1024 + st * 64 + sl) * 3072 + 2048 + h * 64 + h8 * 8);
  }
  __syncthreads();
#pragma unroll
  for (int i = 0; i < 2; ++i) {
    int c = i * 256 + tid;
    int hd = c >> 3, s8 = c & 7;
    s16x8 o;
#pragma unroll
    for (int j = 0; j < 8; ++j) o[j] = (short)tile[s8 * 8 + j][hd];
    *(s16x8*)(vT + ((size_t)bh * 64 + hd) * 1024 + st * 64 + s8 * 8) = o;
  }
}

// fused flash attention v2: QBLK=64, grid (bh fastest, qt).
// 4 waves x 16 t-rows. LDS 40KB: Q[64][128B] (reused as per-wave P), K,V dbuf.
// S/O row t = (lane>>4)*4 + j across fr=lane&15 cols.
__global__ __launch_bounds__(256) void attn_flash(const u16* __restrict__ qkv,
    const u16* __restrict__ vT, float* __restrict__ x) {
  const int bh = blockIdx.x;           // fastest -> XCD = bh%8, balanced + K/V L2 reuse
  const int qt = blockIdx.y;
  const int b = bh >> 4, h = bh & 15;
  __shared__ __align__(128) char lds[40960];
  char* Qs = lds;                      // [64][128B] = 8KB; wave w's rows reused as its P
  char* Ks = lds + 8192;               // 2 x [64][128B]
  char* Vs = lds + 24576;              // 2 x [64][128B]
  const int tid = threadIdx.x, lane = tid & 63, w = tid >> 6;
  const int fr = lane & 15, k8 = lane >> 4;
  char* Pw = Qs + w * 2048;            // [16][128B]
  const u16* qbase = qkv + (size_t)(b * 1024 + qt * 64) * 3072 + h * 64;
  const u16* kbase = qkv + (size_t)(b * 1024) * 3072 + 1024 + h * 64;
  const u16* vbase = vT + (size_t)bh * 65536;

  stage64<64>(qbase, 3072, Qs, tid);
  stage64<64>(kbase, 3072, Ks, tid);
  stage64<64>(vbase, 1024, Vs, tid);
  __syncthreads();

  bf16x8 aq[2];
#pragma unroll
  for (int kk = 0; kk < 2; ++kk)
    aq[kk] = ldread64(Qs, w * 16 + fr, kk * 4 + k8);
  // P writes into this region are data-dependent on aq (via sacc), so no barrier needed.

  const f32x4 vz = {0.f, 0.f, 0.f, 0.f};
  f32x4 oacc[4];
  f32x4 m_ = {-1e30f, -1e30f, -1e30f, -1e30f};
  f32x4 l_ = vz;
#pragma unroll
  for (int ni = 0; ni < 4; ++ni) oacc[ni] = vz;

  const int nst = qt + 1;
  const int t0 = qt * 64 + w * 16;     // wave's first global t-row
  int cur = 0;
  for (int st = 0; st < nst; ++st) {
    if (st + 1 < nst) {
      stage64<64>(kbase + (size_t)(st + 1) * 64 * 3072, 3072, Ks + (cur ^ 1) * 8192, tid);
      stage64<64>(vbase + (st + 1) * 64, 1024, Vs + (cur ^ 1) * 8192, tid);
    }
    const char* Kc = Ks + cur * 8192;
    const char* Vc = Vs + cur * 8192;
    f32x4 sacc[4];
#pragma unroll
    for (int ni = 0; ni < 4; ++ni) sacc[ni] = vz;
#pragma unroll
    for (int kk = 0; kk < 2; ++kk) {
      bf16x8 bk[4];
#pragma unroll
      for (int ni = 0; ni < 4; ++ni) bk[ni] = ldread64(Kc, ni * 16 + fr, kk * 4 + k8);
#pragma unroll
      for (int ni = 0; ni < 4; ++ni)
        sacc[ni] = __builtin_amdgcn_mfma_f32_16x16x32_bf16(aq[kk], bk[ni], sacc[ni], 0, 0, 0);
    }
    const int sbase = st * 64;
    const bool needMask = (st == qt);
#pragma unroll
    for (int ni = 0; ni < 4; ++ni) {
      sacc[ni] *= 0.125f;
      if (needMask) {
        const int s = sbase + ni * 16 + fr;
#pragma unroll
        for (int j = 0; j < 4; ++j) {
          const int t = t0 + k8 * 4 + j;
          if (s > t) sacc[ni][j] = -1e30f;
        }
      }
    }
    f32x4 pm = fmax4(fmax4(sacc[0], sacc[1]), fmax4(sacc[2], sacc[3]));
#pragma unroll
    for (int msk = 1; msk <= 8; msk <<= 1) {
#pragma unroll
      for (int j = 0; j < 4; ++j) pm[j] = fmaxf(pm[j], __shfl_xor(pm[j], msk));
    }
    const f32x4 mn = fmax4(m_, pm);
    f32x4 alpha, rs = vz;
#pragma unroll
    for (int j = 0; j < 4; ++j) alpha[j] = __expf(m_[j] - mn[j]);
#pragma unroll
    for (int ni = 0; ni < 4; ++ni) {
#pragma unroll
      for (int j = 0; j < 4; ++j) {
        const float p = __expf(sacc[ni][j] - mn[j]);
        rs[j] += p;
        const int t_loc = k8 * 4 + j;
        const int s_loc = ni * 16 + fr;
        *(u16*)(Pw + t_loc * 128 + (((s_loc >> 3) ^ (t_loc & 7)) << 4) + (s_loc & 7) * 2) = f2b(p);
      }
    }
#pragma unroll
    for (int msk = 1; msk <= 8; msk <<= 1) {
#pragma unroll
      for (int j = 0; j < 4; ++j) rs[j] += __shfl_xor(rs[j], msk);
    }
    m_ = mn;
#pragma unroll
    for (int j = 0; j < 4; ++j) l_[j] = l_[j] * alpha[j] + rs[j];
#pragma unroll
    for (int ni = 0; ni < 4; ++ni) oacc[ni] *= alpha;
    // PV: A = P (own wave region), B = V^T
#pragma unroll
    for (int kk = 0; kk < 2; ++kk) {
      bf16x8 ap = ldread64(Pw, fr, kk * 4 + k8);
      bf16x8 bv[4];
#pragma unroll
      for (int ni = 0; ni < 4; ++ni) bv[ni] = ldread64(Vc, ni * 16 + fr, kk * 4 + k8);
#pragma unroll
      for (int ni = 0; ni < 4; ++ni)
        oacc[ni] = __builtin_amdgcn_mfma_f32_16x16x32_bf16(ap, bv[ni], oacc[ni], 0, 0, 0);
    }
    __syncthreads();
    cur ^= 1;
  }
  // epilogue: O /= l, accumulate into residual x
  f32x4 invl;
#pragma unroll
  for (int j = 0; j < 4; ++j) invl[j] = 1.f / l_[j];
#pragma unroll
  for (int ni = 0; ni < 4; ++ni) {
    const int hd = ni * 16 + fr;
#pragma unroll
    for (int j = 0; j < 4; ++j) {
      const int t = t0 + k8 * 4 + j;
      x[(size_t)(b * 1024 + t) * 1024 + h * 64 + hd] += oacc[ni][j] * invl[j];
    }
  }
}

// in-place softmax over V=32000, float4-vectorized
__global__ __launch_bounds__(256) void softmax_v(float* __restrict__ logits) {
  const int row = blockIdx.x, tid = threadIdx.x;
  float* lr = logits + (size_t)row * 32000;
  const float4* lr4 = (const float4*)lr;
  float mx = -1e30f, sm = 0.f;
  for (int i = tid; i < 8000; i += 256) {
    const float4 v = lr4[i];
    float vm = fmaxf(fmaxf(v.x, v.y), fmaxf(v.z, v.w));
    float m2 = fmaxf(mx, vm);
    sm = sm * __expf(mx - m2) + __expf(v.x - m2) + __expf(v.y - m2) +
         __expf(v.z - m2) + __expf(v.w - m2);
    mx = m2;
  }
  __shared__ float smx[4], ssm[4];
#pragma unroll
  for (int off = 32; off >= 1; off >>= 1) {
    float om = __shfl_down(mx, off), os = __shfl_down(sm, off);
    float m2 = fmaxf(mx, om);
    sm = sm * __expf(mx - m2) + os * __expf(om - m2);
    mx = m2;
  }
  if ((tid & 63) == 0) { smx[tid >> 6] = mx; ssm[tid >> 6] = sm; }
  __syncthreads();
  const float M = fmaxf(fmaxf(smx[0], smx[1]), fmaxf(smx[2], smx[3]));
  const float S = ssm[0] * __expf(smx[0] - M) + ssm[1] * __expf(smx[1] - M) +
                  ssm[2] * __expf(smx[2] - M) + ssm[3] * __expf(smx[3] - M);
  const float inv = 1.f / S;
  float4* lw4 = (float4*)lr;
  for (int i = tid; i < 8000; i += 256) {
    float4 v = lw4[i];
    v.x = __expf(v.x - M) * inv; v.y = __expf(v.y - M) * inv;
    v.z = __expf(v.z - M) * inv; v.w = __expf(v.w - M) * inv;
    lw4[i] = v;
  }
}

// ---------------- host ----------------

extern "C" void kernel_launch(void* const* d_in, const int* in_sizes, int n_in,
                              void* d_out, int out_size, void* d_ws, size_t ws_size,
                              hipStream_t stream) {
  const int*   ctx   = (const int*)d_in[0];
  const float* tok   = (const float*)d_in[1];
  const float* pos   = (const float*)d_in[2];
  const float* wq    = (const float*)d_in[3];
  const float* wk    = (const float*)d_in[4];
  const float* wv    = (const float*)d_in[5];
  const float* ln1_s = (const float*)d_in[6];
  const float* ln1_b = (const float*)d_in[7];
  const float* ln2_s = (const float*)d_in[8];
  const float* ln2_b = (const float*)d_in[9];
  const float* fw1   = (const float*)d_in[10];
  const float* fb1   = (const float*)d_in[11];
  const float* fw2   = (const float*)d_in[12];
  const float* fb2   = (const float*)d_in[13];
  const float* lnf_s = (const float*)d_in[14];
  const float* lnf_b = (const float*)d_in[15];
  const float* wp    = (const float*)d_in[16];
  const float* bp    = (const float*)d_in[17];
  float* out = (float*)d_out;

  char* ws = (char*)d_ws;
  size_t o = 0;
  auto get = [&](size_t bytes) {
    char* r = ws + o;
    o += (bytes + 255) & ~(size_t)255;
    return r;
  };
  u16*   wqkvT = (u16*)get(12ULL * 3072 * 1024 * 2);
  u16*   wf1T  = (u16*)get(12ULL * 1024 * 1024 * 2);
  u16*   wf2T  = (u16*)get(12ULL * 1024 * 1024 * 2);
  u16*   wpT   = (u16*)get(32000ULL * 1024 * 2);
  float* x     = (float*)get(2048ULL * 1024 * 4);
  u16*   h     = (u16*)get(2048ULL * 1024 * 2);
  u16*   qkvb  = (u16*)get(2048ULL * 3072 * 2);
  u16*   vT    = (u16*)get(32ULL * 64 * 1024 * 2);
  u16*   f1b   = (u16*)get(2048ULL * 1024 * 2);

  embed_kernel<<<2048, 256, 0, stream>>>(ctx, tok, pos, x);
  transpose_qkv<<<dim3(32, 32, 36), 256, 0, stream>>>(wq, wk, wv, wqkvT);
  transpose_cvt<<<dim3(32, 32, 12), 256, 0, stream>>>(fw1, wf1T, 1024, 1048576, 1048576);
  transpose_cvt<<<dim3(32, 32, 12), 256, 0, stream>>>(fw2, wf2T, 1024, 1048576, 1048576);
  transpose_cvt<<<dim3(1000, 32, 1), 256, 0, stream>>>(wp, wpT, 32000, 0, 0);

  for (int l = 0; l < 12; ++l) {
    layernorm_bf16<<<2048, 256, 0, stream>>>(x, ln1_s + l * 1024, ln1_b + l * 1024, h);
    gemm_bt<4, 4, 2, 2, false, false, false, true, false, 0><<<dim3(24, 16), 256, 0, stream>>>(
        h, 1024, wqkvT + (size_t)l * 3145728, 1024, nullptr, nullptr, qkvb, 3072, 32);
    gather_vT<<<dim3(16, 32), 256, 0, stream>>>(qkvb, vT);
    attn_flash<<<dim3(32, 16), 256, 0, stream>>>(qkvb, vT, x);
    layernorm_bf16<<<2048, 256, 0, stream>>>(x, ln2_s + l * 1024, ln2_b + l * 1024, h);
    gemm_bt<4, 2, 2, 2, true, true, false, true, false, 0><<<dim3(16, 16), 256, 0, stream>>>(
        h, 1024, wf1T + (size_t)l * 1048576, 1024, fb1 + l * 1024, nullptr, f1b, 1024, 32);
    gemm_bt<4, 2, 2, 2, true, false, true, false, false, 0><<<dim3(16, 16), 256, 0, stream>>>(
        f1b, 1024, wf2T + (size_t)l * 1048576, 1024, fb2 + l * 1024, x, x, 1024, 32);
  }

  layernorm_bf16<<<2048, 256, 0, stream>>>(x, lnf_s, lnf_b, h);
  // vocab GEMM: 1-D grid 4000, bijective XCD swizzle (SWIZ = 4000/8 = 500)
  gemm_bt<4, 4, 2, 2, true, false, false, false, false, 500><<<dim3(4000), 256, 0, stream>>>(
      h, 1024, wpT, 1024, bp, nullptr, out, 32000, 32);
  softmax_v<<<2048, 256, 0, stream>>>(out);
}

// Round 5
// 2079.534 us; speedup vs baseline: 1.5791x; 1.0569x over previous
//
#include <hip/hip_runtime.h>
#include <hip/hip_bf16.h>

typedef unsigned short u16;
typedef float f32x4 __attribute__((ext_vector_type(4)));
typedef __bf16 bf16x8 __attribute__((ext_vector_type(8)));
typedef short s16x8 __attribute__((ext_vector_type(8)));

// ---------------- helpers ----------------

__device__ __forceinline__ u16 f2b(float f) {
  union { __hip_bfloat16 h; u16 u; } c;
  c.h = __float2bfloat16(f);
  return c.u;
}

__device__ __forceinline__ float b2f(u16 u) {
  union { unsigned i; float f; } c;
  c.i = (unsigned)u << 16;
  return c.f;
}

__device__ __forceinline__ void gload16(const void* g, void* l) {
  __builtin_amdgcn_global_load_lds(
      (const __attribute__((address_space(1))) unsigned int*)g,
      (__attribute__((address_space(3))) unsigned int*)l, 16, 0, 0);
}

__device__ __forceinline__ float block_sum(float v, float* sred) {
  const int tid = threadIdx.x;
#pragma unroll
  for (int off = 32; off >= 1; off >>= 1) v += __shfl_down(v, off);
  if ((tid & 63) == 0) sred[tid >> 6] = v;
  __syncthreads();
  float r = sred[0] + sred[1] + sred[2] + sred[3];
  __syncthreads();
  return r;
}

__device__ __forceinline__ f32x4 fmax4(f32x4 a, f32x4 b) {
  f32x4 r;
  r[0] = fmaxf(a[0], b[0]); r[1] = fmaxf(a[1], b[1]);
  r[2] = fmaxf(a[2], b[2]); r[3] = fmaxf(a[3], b[3]);
  return r;
}

// ---------------- GEMM core (64 B rows = 32 bf16 K-slab) ----------------
// LDS tile row-major [ROWS][32] bf16, 16B slots XOR-swizzled slot'=k8^((row>>1)&3).
// Swizzle applied on the GLOBAL source (global_load_lds dest must be linear),
// identical XOR on the ds_read side.

template<int ROWS>
__device__ __forceinline__ void stage_tile(const u16* g, int ld, char* ldsb, int tid) {
#pragma unroll
  for (int i = 0; i < ROWS / 64; ++i) {
    int c = i * 256 + tid;
    int row = c >> 2;
    int k8 = (c & 3) ^ ((row >> 1) & 3);
    gload16(g + (size_t)row * ld + k8 * 8, ldsb + i * 4096 + (tid & 192) * 16);
  }
}

template<int MI, int NI, int WCN>
__device__ __forceinline__ void compute_tile(const char* lA, const char* lB, f32x4 (&acc)[MI][NI]) {
  const int tid = threadIdx.x;
  const int lane = tid & 63;
  const int w = tid >> 6;
  const int wr = w / WCN, wc = w % WCN;
  const int fr = lane & 15, k8 = lane >> 4;
  bf16x8 a[MI], b[NI];
#pragma unroll
  for (int mi = 0; mi < MI; ++mi) {
    int row = wr * (MI * 16) + mi * 16 + fr;
    a[mi] = *(const bf16x8*)(lA + row * 64 + ((k8 ^ ((row >> 1) & 3)) << 4));
  }
#pragma unroll
  for (int ni = 0; ni < NI; ++ni) {
    int row = wc * (NI * 16) + ni * 16 + fr;
    b[ni] = *(const bf16x8*)(lB + row * 64 + ((k8 ^ ((row >> 1) & 3)) << 4));
  }
#pragma unroll
  for (int mi = 0; mi < MI; ++mi)
#pragma unroll
    for (int ni = 0; ni < NI; ++ni)
      acc[mi][ni] = __builtin_amdgcn_mfma_f32_16x16x32_bf16(a[mi], b[ni], acc[mi][ni], 0, 0, 0);
}

template<int MI, int NI, int WRN, int WCN, int BMT, int BNT>
__device__ __forceinline__ void gemm_core(const u16* A, int lda, const u16* B, int ldb,
                                          int nkt, char* lds, f32x4 (&acc)[MI][NI]) {
  const int tid = threadIdx.x;
  const int bufSz = BMT * 64 + BNT * 64;
  stage_tile<BMT>(A, lda, lds, tid);
  stage_tile<BNT>(B, ldb, lds + BMT * 64, tid);
  __syncthreads();
  int cur = 0;
  for (int kt = 0; kt < nkt; ++kt) {
    if (kt + 1 < nkt) {
      char* nb = lds + (cur ^ 1) * bufSz;
      stage_tile<BMT>(A + (size_t)(kt + 1) * 32, lda, nb, tid);
      stage_tile<BNT>(B + (size_t)(kt + 1) * 32, ldb, nb + BMT * 64, tid);
    }
    char* cb = lds + cur * bufSz;
    compute_tile<MI, NI, WCN>(cb, cb + BMT * 64, acc);
    __syncthreads();
    cur ^= 1;
  }
}

// ---------------- flash-attn staging (128 B rows = 64 bf16) ----------------
// slot' = slot ^ (row&7): conflict-free ds_read_b128 of [row][64] tiles.

template<int ROWS>
__device__ __forceinline__ void stage64(const u16* g, int ld, char* ldsb, int tid) {
#pragma unroll
  for (int i = 0; i < ROWS / 32; ++i) {
    int c = i * 256 + tid;
    int row = c >> 3;
    int slot = (c & 7) ^ (row & 7);
    gload16(g + (size_t)row * ld + slot * 8, ldsb + i * 4096 + (tid & 192) * 16);
  }
}

__device__ __forceinline__ bf16x8 ldread64(const char* base, int row, int slot) {
  return *(const bf16x8*)(base + row * 128 + ((slot ^ (row & 7)) << 4));
}

// ---------------- kernels ----------------

__global__ __launch_bounds__(256) void embed_kernel(const int* __restrict__ ctx,
    const float* __restrict__ tok, const float* __restrict__ pos, float* __restrict__ x) {
  const int row = blockIdx.x, tid = threadIdx.x;
  const int t = row & 1023;
  const int id = ctx[row];
  float4 a = ((const float4*)(tok + (size_t)id * 1024))[tid];
  float4 p = ((const float4*)(pos + (size_t)t * 1024))[tid];
  a.x += p.x; a.y += p.y; a.z += p.z; a.w += p.w;
  ((float4*)(x + (size_t)row * 1024))[tid] = a;
}

__global__ __launch_bounds__(256) void layernorm_bf16(const float* __restrict__ x,
    const float* __restrict__ sc, const float* __restrict__ bi, u16* __restrict__ h) {
  __shared__ float sred[4];
  const int row = blockIdx.x, tid = threadIdx.x;
  const float4 v = ((const float4*)(x + (size_t)row * 1024))[tid];
  float mean = block_sum(v.x + v.y + v.z + v.w, sred) * (1.f / 1024.f);
  const float dx = v.x - mean, dy = v.y - mean, dz = v.z - mean, dw = v.w - mean;
  float var = block_sum(dx * dx + dy * dy + dz * dz + dw * dw, sred) * (1.f / 1024.f);
  const float rs = rsqrtf(var + 1e-5f);
  const float4 s4 = ((const float4*)sc)[tid];
  const float4 b4 = ((const float4*)bi)[tid];
  ushort4 o;
  o.x = f2b(dx * rs * s4.x + b4.x);
  o.y = f2b(dy * rs * s4.y + b4.y);
  o.z = f2b(dz * rs * s4.z + b4.z);
  o.w = f2b(dw * rs * s4.w + b4.w);
  ((ushort4*)(h + (size_t)row * 1024))[tid] = o;
}

__device__ __forceinline__ void transpose_body(const float* __restrict__ src,
                                               u16* __restrict__ dst, int N) {
  __shared__ float tile[32][33];
  const int tid = threadIdx.x;
  const int tx = tid & 31, ty = tid >> 5;
  const int kt = blockIdx.y * 32, nt = blockIdx.x * 32;
#pragma unroll
  for (int i = 0; i < 4; ++i) {
    int r = ty + i * 8;
    tile[r][tx] = src[(size_t)(kt + r) * N + nt + tx];
  }
  __syncthreads();
#pragma unroll
  for (int i = 0; i < 4; ++i) {
    int r = ty + i * 8;
    dst[(size_t)(nt + r) * 1024 + kt + tx] = f2b(tile[tx][r]);
  }
}

__global__ __launch_bounds__(256) void transpose_cvt(const float* __restrict__ src,
    u16* __restrict__ dst, int N, size_t srcStride, size_t dstStride) {
  transpose_body(src + blockIdx.z * srcStride, dst + blockIdx.z * dstStride, N);
}

__global__ __launch_bounds__(256) void transpose_qkv(const float* __restrict__ wq,
    const float* __restrict__ wk, const float* __restrict__ wv, u16* __restrict__ dst) {
  const int z = blockIdx.z, l = z / 3, which = z - l * 3;
  const float* src = (which == 0 ? wq : (which == 1 ? wk : wv)) + (size_t)l * 1048576;
  u16* d = dst + (size_t)l * 3145728 + (size_t)which * 1048576;
  transpose_body(src, d, 1024);
}

// generic C = A@Bt^T. Tile = (WRN*MI*16) x (WCN*NI*16). XSWAP: grid.x = M tiles.
// SWIZ>0: 1-D grid of 8*SWIZ blocks; v'=(v%8)*SWIZ+v/8, bni=v'/16, bmi=v'%16
// (n-major per XCD -> each B-panel fetched by exactly one XCD's L2).
template<int MI, int NI, int WRN, int WCN, bool BIAS, bool RELU, bool RESID, bool OUTBF,
         bool XSWAP, int SWIZ>
__global__ __launch_bounds__(256) void gemm_bt(const u16* __restrict__ A, int lda,
    const u16* __restrict__ Bt, int ldb, const float* __restrict__ bias,
    const float* __restrict__ resid, void* __restrict__ out, int ldc, int nkt) {
  constexpr int BMT = WRN * MI * 16;
  constexpr int BNT = WCN * NI * 16;
  __shared__ __align__(128) char lds[2 * (BMT * 64 + BNT * 64)];
  int bmi, bni;
  if (SWIZ > 0) {
    const int v = blockIdx.x;
    const int vp = (v & 7) * SWIZ + (v >> 3);
    bni = vp >> 4;
    bmi = vp & 15;
  } else {
    bmi = XSWAP ? blockIdx.x : blockIdx.y;
    bni = XSWAP ? blockIdx.y : blockIdx.x;
  }
  const size_t bm = (size_t)bmi * BMT, bn = (size_t)bni * BNT;
  const f32x4 vz = {0.f, 0.f, 0.f, 0.f};
  f32x4 acc[MI][NI];
#pragma unroll
  for (int i = 0; i < MI; ++i)
#pragma unroll
    for (int j = 0; j < NI; ++j) acc[i][j] = vz;
  gemm_core<MI, NI, WRN, WCN, BMT, BNT>(A + bm * lda, lda, Bt + bn * ldb, ldb, nkt, lds, acc);
  const int tid = threadIdx.x, lane = tid & 63, w = tid >> 6;
  const int wr = w / WCN, wc = w % WCN, fr = lane & 15, k8 = lane >> 4;
#pragma unroll
  for (int mi = 0; mi < MI; ++mi)
#pragma unroll
    for (int ni = 0; ni < NI; ++ni) {
      const size_t c = bn + wc * (NI * 16) + ni * 16 + fr;
      const float bv = BIAS ? bias[c] : 0.f;
#pragma unroll
      for (int j = 0; j < 4; ++j) {
        const size_t r = bm + wr * (MI * 16) + mi * 16 + k8 * 4 + j;
        float v = acc[mi][ni][j] + bv;
        if (RELU) v = fmaxf(v, 0.f);
        if (RESID) v += resid[r * (size_t)ldc + c];
        if (OUTBF) ((u16*)out)[r * (size_t)ldc + c] = f2b(v);
        else       ((float*)out)[r * (size_t)ldc + c] = v;
      }
    }
}

// QKV GEMM 128x64 tiles, grid (48 N-tiles, 16 M-tiles).
// bni 0..31 (Q,K) -> qkvb[r][c] bf16; bni 32..47 (V head h=bni-32) -> vT[bh][hd][s].
__global__ __launch_bounds__(256) void qkv_gemm(const u16* __restrict__ A,
    const u16* __restrict__ Bt, u16* __restrict__ qkvb, u16* __restrict__ vT) {
  __shared__ __align__(128) char lds[2 * (128 * 64 + 64 * 64)];
  const int bni = blockIdx.x, bmi = blockIdx.y;
  const size_t bm = (size_t)bmi * 128, bn = (size_t)bni * 64;
  const f32x4 vz = {0.f, 0.f, 0.f, 0.f};
  f32x4 acc[4][2];
#pragma unroll
  for (int i = 0; i < 4; ++i)
#pragma unroll
    for (int j = 0; j < 2; ++j) acc[i][j] = vz;
  gemm_core<4, 2, 2, 2, 128, 64>(A + bm * 1024, 1024, Bt + bn * 1024, 1024, 32, lds, acc);
  const int tid = threadIdx.x, lane = tid & 63, w = tid >> 6;
  const int wr = w >> 1, wc = w & 1, fr = lane & 15, k8 = lane >> 4;
  if (bni < 32) {
#pragma unroll
    for (int mi = 0; mi < 4; ++mi)
#pragma unroll
      for (int ni = 0; ni < 2; ++ni) {
        const size_t c = bn + wc * 32 + ni * 16 + fr;
#pragma unroll
        for (int j = 0; j < 4; ++j) {
          const size_t r = bm + wr * 64 + mi * 16 + k8 * 4 + j;
          qkvb[r * 3072 + c] = f2b(acc[mi][ni][j]);
        }
      }
  } else {
    const int h = bni - 32;
    const int b = (int)(bm >> 10);
#pragma unroll
    for (int mi = 0; mi < 4; ++mi)
#pragma unroll
      for (int ni = 0; ni < 2; ++ni) {
        const int hd = wc * 32 + ni * 16 + fr;
        const size_t rowV = ((size_t)(b * 16 + h)) * 64 + hd;
        const int s0 = (int)((bm & 1023) + wr * 64 + mi * 16 + k8 * 4);
        ushort4 q;
        q.x = f2b(acc[mi][ni][0]); q.y = f2b(acc[mi][ni][1]);
        q.z = f2b(acc[mi][ni][2]); q.w = f2b(acc[mi][ni][3]);
        *(ushort4*)(vT + rowV * 1024 + s0) = q;
      }
  }
}

// fused flash attention v2: QBLK=64, grid (bh fastest, qt).
// 4 waves x 16 t-rows. LDS 40KB: Q[64][128B] (reused as per-wave P), K,V dbuf.
__global__ __launch_bounds__(256) void attn_flash(const u16* __restrict__ qkv,
    const u16* __restrict__ vT, float* __restrict__ x) {
  const int bh = blockIdx.x;           // fastest -> XCD = bh%8, balanced + K/V L2 reuse
  const int qt = blockIdx.y;
  const int b = bh >> 4, h = bh & 15;
  __shared__ __align__(128) char lds[40960];
  char* Qs = lds;                      // [64][128B]; wave w's rows reused as its P
  char* Ks = lds + 8192;               // 2 x [64][128B]
  char* Vs = lds + 24576;              // 2 x [64][128B]
  const int tid = threadIdx.x, lane = tid & 63, w = tid >> 6;
  const int fr = lane & 15, k8 = lane >> 4;
  char* Pw = Qs + w * 2048;            // [16][128B]
  const u16* qbase = qkv + (size_t)(b * 1024 + qt * 64) * 3072 + h * 64;
  const u16* kbase = qkv + (size_t)(b * 1024) * 3072 + 1024 + h * 64;
  const u16* vbase = vT + (size_t)bh * 65536;

  stage64<64>(qbase, 3072, Qs, tid);
  stage64<64>(kbase, 3072, Ks, tid);
  stage64<64>(vbase, 1024, Vs, tid);
  __syncthreads();

  bf16x8 aq[2];
#pragma unroll
  for (int kk = 0; kk < 2; ++kk)
    aq[kk] = ldread64(Qs, w * 16 + fr, kk * 4 + k8);

  const f32x4 vz = {0.f, 0.f, 0.f, 0.f};
  f32x4 oacc[4];
  f32x4 m_ = {-1e30f, -1e30f, -1e30f, -1e30f};
  f32x4 l_ = vz;
#pragma unroll
  for (int ni = 0; ni < 4; ++ni) oacc[ni] = vz;

  const int nst = qt + 1;
  const int t0 = qt * 64 + w * 16;
  int cur = 0;
  for (int st = 0; st < nst; ++st) {
    if (st + 1 < nst) {
      stage64<64>(kbase + (size_t)(st + 1) * 64 * 3072, 3072, Ks + (cur ^ 1) * 8192, tid);
      stage64<64>(vbase + (st + 1) * 64, 1024, Vs + (cur ^ 1) * 8192, tid);
    }
    const char* Kc = Ks + cur * 8192;
    const char* Vc = Vs + cur * 8192;
    f32x4 sacc[4];
#pragma unroll
    for (int ni = 0; ni < 4; ++ni) sacc[ni] = vz;
#pragma unroll
    for (int kk = 0; kk < 2; ++kk) {
      bf16x8 bk[4];
#pragma unroll
      for (int ni = 0; ni < 4; ++ni) bk[ni] = ldread64(Kc, ni * 16 + fr, kk * 4 + k8);
#pragma unroll
      for (int ni = 0; ni < 4; ++ni)
        sacc[ni] = __builtin_amdgcn_mfma_f32_16x16x32_bf16(aq[kk], bk[ni], sacc[ni], 0, 0, 0);
    }
    const int sbase = st * 64;
    const bool needMask = (st == qt);
#pragma unroll
    for (int ni = 0; ni < 4; ++ni) {
      sacc[ni] *= 0.125f;
      if (needMask) {
        const int s = sbase + ni * 16 + fr;
#pragma unroll
        for (int j = 0; j < 4; ++j) {
          const int t = t0 + k8 * 4 + j;
          if (s > t) sacc[ni][j] = -1e30f;
        }
      }
    }
    f32x4 pm = fmax4(fmax4(sacc[0], sacc[1]), fmax4(sacc[2], sacc[3]));
#pragma unroll
    for (int msk = 1; msk <= 8; msk <<= 1) {
#pragma unroll
      for (int j = 0; j < 4; ++j) pm[j] = fmaxf(pm[j], __shfl_xor(pm[j], msk));
    }
    const f32x4 mn = fmax4(m_, pm);
    f32x4 alpha, rs = vz;
#pragma unroll
    for (int j = 0; j < 4; ++j) alpha[j] = __expf(m_[j] - mn[j]);
#pragma unroll
    for (int ni = 0; ni < 4; ++ni) {
#pragma unroll
      for (int j = 0; j < 4; ++j) {
        const float p = __expf(sacc[ni][j] - mn[j]);
        rs[j] += p;
        const int t_loc = k8 * 4 + j;
        const int s_loc = ni * 16 + fr;
        *(u16*)(Pw + t_loc * 128 + (((s_loc >> 3) ^ (t_loc & 7)) << 4) + (s_loc & 7) * 2) = f2b(p);
      }
    }
#pragma unroll
    for (int msk = 1; msk <= 8; msk <<= 1) {
#pragma unroll
      for (int j = 0; j < 4; ++j) rs[j] += __shfl_xor(rs[j], msk);
    }
    m_ = mn;
#pragma unroll
    for (int j = 0; j < 4; ++j) l_[j] = l_[j] * alpha[j] + rs[j];
#pragma unroll
    for (int ni = 0; ni < 4; ++ni) oacc[ni] *= alpha;
#pragma unroll
    for (int kk = 0; kk < 2; ++kk) {
      bf16x8 ap = ldread64(Pw, fr, kk * 4 + k8);
      bf16x8 bv[4];
#pragma unroll
      for (int ni = 0; ni < 4; ++ni) bv[ni] = ldread64(Vc, ni * 16 + fr, kk * 4 + k8);
#pragma unroll
      for (int ni = 0; ni < 4; ++ni)
        oacc[ni] = __builtin_amdgcn_mfma_f32_16x16x32_bf16(ap, bv[ni], oacc[ni], 0, 0, 0);
    }
    __syncthreads();
    cur ^= 1;
  }
  f32x4 invl;
#pragma unroll
  for (int j = 0; j < 4; ++j) invl[j] = 1.f / l_[j];
#pragma unroll
  for (int ni = 0; ni < 4; ++ni) {
    const int hd = ni * 16 + fr;
#pragma unroll
    for (int j = 0; j < 4; ++j) {
      const int t = t0 + k8 * 4 + j;
      x[(size_t)(b * 1024 + t) * 1024 + h * 64 + hd] += oacc[ni][j] * invl[j];
    }
  }
}

// softmax over V=32000 from bf16 logits, row held in registers (16 chunks x 8 bf16).
__global__ __launch_bounds__(256) void softmax_v2(const u16* __restrict__ lg,
                                                  float* __restrict__ out) {
  const int row = blockIdx.x, tid = threadIdx.x;
  const u16* lr = lg + (size_t)row * 32000;
  float* orow = out + (size_t)row * 32000;
  s16x8 buf[16];
  float mx = -1e30f;
#pragma unroll
  for (int c = 0; c < 16; ++c) {
    const int idx = tid + c * 256;
    if (idx < 4000) {
      buf[c] = *(const s16x8*)(lr + idx * 8);
#pragma unroll
      for (int j = 0; j < 8; ++j) mx = fmaxf(mx, b2f((u16)buf[c][j]));
    }
  }
  __shared__ float smx[4], ssum[4];
#pragma unroll
  for (int off = 32; off >= 1; off >>= 1) mx = fmaxf(mx, __shfl_down(mx, off));
  if ((tid & 63) == 0) smx[tid >> 6] = mx;
  __syncthreads();
  const float M = fmaxf(fmaxf(smx[0], smx[1]), fmaxf(smx[2], smx[3]));
  __syncthreads();
  float sm = 0.f;
#pragma unroll
  for (int c = 0; c < 16; ++c) {
    const int idx = tid + c * 256;
    if (idx < 4000) {
#pragma unroll
      for (int j = 0; j < 8; ++j) sm += __expf(b2f((u16)buf[c][j]) - M);
    }
  }
  const float S = block_sum(sm, ssum);
  const float inv = 1.f / S;
#pragma unroll
  for (int c = 0; c < 16; ++c) {
    const int idx = tid + c * 256;
    if (idx < 4000) {
      float4 o0, o1;
      o0.x = __expf(b2f((u16)buf[c][0]) - M) * inv;
      o0.y = __expf(b2f((u16)buf[c][1]) - M) * inv;
      o0.z = __expf(b2f((u16)buf[c][2]) - M) * inv;
      o0.w = __expf(b2f((u16)buf[c][3]) - M) * inv;
      o1.x = __expf(b2f((u16)buf[c][4]) - M) * inv;
      o1.y = __expf(b2f((u16)buf[c][5]) - M) * inv;
      o1.z = __expf(b2f((u16)buf[c][6]) - M) * inv;
      o1.w = __expf(b2f((u16)buf[c][7]) - M) * inv;
      *(float4*)(orow + idx * 8) = o0;
      *(float4*)(orow + idx * 8 + 4) = o1;
    }
  }
}

// ---------------- host ----------------

extern "C" void kernel_launch(void* const* d_in, const int* in_sizes, int n_in,
                              void* d_out, int out_size, void* d_ws, size_t ws_size,
                              hipStream_t stream) {
  const int*   ctx   = (const int*)d_in[0];
  const float* tok   = (const float*)d_in[1];
  const float* pos   = (const float*)d_in[2];
  const float* wq    = (const float*)d_in[3];
  const float* wk    = (const float*)d_in[4];
  const float* wv    = (const float*)d_in[5];
  const float* ln1_s = (const float*)d_in[6];
  const float* ln1_b = (const float*)d_in[7];
  const float* ln2_s = (const float*)d_in[8];
  const float* ln2_b = (const float*)d_in[9];
  const float* fw1   = (const float*)d_in[10];
  const float* fb1   = (const float*)d_in[11];
  const float* fw2   = (const float*)d_in[12];
  const float* fb2   = (const float*)d_in[13];
  const float* lnf_s = (const float*)d_in[14];
  const float* lnf_b = (const float*)d_in[15];
  const float* wp    = (const float*)d_in[16];
  const float* bp    = (const float*)d_in[17];
  float* out = (float*)d_out;

  // ws layout: wpT FIRST so bf16 logits can alias the (then-dead) layer weights.
  char* ws = (char*)d_ws;
  size_t o = 0;
  auto get = [&](size_t bytes) {
    char* r = ws + o;
    o += (bytes + 255) & ~(size_t)255;
    return r;
  };
  u16*   wpT   = (u16*)get(32000ULL * 1024 * 2);      // 65.5 MB
  size_t aliasOff = o;
  u16*   wqkvT = (u16*)get(12ULL * 3072 * 1024 * 2);  // 75.5 MB
  u16*   wf1T  = (u16*)get(12ULL * 1024 * 1024 * 2);  // 25.2 MB
  u16*   wf2T  = (u16*)get(12ULL * 1024 * 1024 * 2);  // 25.2 MB
  float* x     = (float*)get(2048ULL * 1024 * 4);     // 8.4 MB
  u16*   h     = (u16*)get(2048ULL * 1024 * 2);
  u16*   qkvb  = (u16*)get(2048ULL * 3072 * 2);
  u16*   vT    = (u16*)get(32ULL * 64 * 1024 * 2);
  u16*   f1b   = (u16*)get(2048ULL * 1024 * 2);
  // bf16 logits (131 MB) alias wqkvT+wf1T+wf2T+x (134.2 MB) - all dead by then.
  u16*   logitsb = (u16*)(ws + aliasOff);

  embed_kernel<<<2048, 256, 0, stream>>>(ctx, tok, pos, x);
  transpose_qkv<<<dim3(32, 32, 36), 256, 0, stream>>>(wq, wk, wv, wqkvT);
  transpose_cvt<<<dim3(32, 32, 12), 256, 0, stream>>>(fw1, wf1T, 1024, 1048576, 1048576);
  transpose_cvt<<<dim3(32, 32, 12), 256, 0, stream>>>(fw2, wf2T, 1024, 1048576, 1048576);
  transpose_cvt<<<dim3(1000, 32, 1), 256, 0, stream>>>(wp, wpT, 32000, 0, 0);

  for (int l = 0; l < 12; ++l) {
    layernorm_bf16<<<2048, 256, 0, stream>>>(x, ln1_s + l * 1024, ln1_b + l * 1024, h);
    qkv_gemm<<<dim3(48, 16), 256, 0, stream>>>(h, wqkvT + (size_t)l * 3145728, qkvb, vT);
    attn_flash<<<dim3(32, 16), 256, 0, stream>>>(qkvb, vT, x);
    layernorm_bf16<<<2048, 256, 0, stream>>>(x, ln2_s + l * 1024, ln2_b + l * 1024, h);
    gemm_bt<2, 2, 2, 2, true, true, false, true, false, 0><<<dim3(16, 32), 256, 0, stream>>>(
        h, 1024, wf1T + (size_t)l * 1048576, 1024, fb1 + l * 1024, nullptr, f1b, 1024, 32);
    gemm_bt<2, 2, 2, 2, true, false, true, false, false, 0><<<dim3(16, 32), 256, 0, stream>>>(
        f1b, 1024, wf2T + (size_t)l * 1048576, 1024, fb2 + l * 1024, x, x, 1024, 32);
  }

  layernorm_bf16<<<2048, 256, 0, stream>>>(x, lnf_s, lnf_b, h);
  // vocab GEMM: 128x64 tiles, 1-D grid 8000, bijective XCD swizzle, bf16 logits out
  gemm_bt<4, 2, 2, 2, true, false, false, true, false, 1000><<<dim3(8000), 256, 0, stream>>>(
      h, 1024, wpT, 1024, bp, nullptr, logitsb, 32000, 32);
  softmax_v2<<<2048, 256, 0, stream>>>(logitsb, out);
}